// Round 17
// baseline (139.386 us; speedup 1.0000x reference)
//
#include <hip/hip_runtime.h>
#include <hip/hip_bf16.h>

// Problem constants
#define C_NUM_CAMS 6
#define C_NUM_LEVELS 4
#define C_NUM_PTS 13
#define C_NUM_GROUPS 8
#define C_BS 2
#define C_NA 900
#define C_E 256
#define C_NSLOT 312      // C*L*P
#define C_NCOL 2496      // NSLOT * G
#define C_NANCH 1800     // BS*NA

// Level geometry: H 64,32,16,8; W 176,88,44,22; HW 11264,2816,704,176
// fp8 buffers: 1 byte/elem, level bases in bytes (same for NCHW and NHWC)
#define LB0 0
#define LB1 34603008     // 12*11264*256
#define LB2 43253760     // +12*2816*256
#define LB3 45416448     // +12*704*256
#define FM8_WS_BYTES 45957120ull
#define WGT16_WS_BYTES 8985600ull  // 1800*2496*2 (bf16 logits)
#define WBT_WS_BYTES 1277952ull    // 2496*256*2
#define NCH16 2872320              // total 16B chunks in fp8 fm space

typedef float floatx2 __attribute__((ext_vector_type(2)));
typedef float f32x4 __attribute__((ext_vector_type(4)));
typedef short s16x8 __attribute__((ext_vector_type(8)));
typedef float f32x4v __attribute__((ext_vector_type(4)));

static __device__ __forceinline__ int pk_fp8(float a, float b, float c, float d) {
  int v = __builtin_amdgcn_cvt_pk_fp8_f32(a, b, 0, false);   // bytes 0,1
  v = __builtin_amdgcn_cvt_pk_fp8_f32(c, d, v, true);        // bytes 2,3
  return v;
}
static __device__ __forceinline__ unsigned short f2bf(float f) {
  __hip_bfloat16 h = __float2bfloat16(f);
  return *reinterpret_cast<unsigned short*>(&h);
}
static __device__ __forceinline__ float bf2f(unsigned short u) {
  unsigned int v = ((unsigned int)u) << 16;
  float f;
  __builtin_memcpy(&f, &v, 4);
  return f;
}

// ---------------------------------------------------------------------------
// K0: prep — coalesced transpose Wwfc f32[256][2496] -> Wbt bf16[2496][256].
// ---------------------------------------------------------------------------
__global__ __launch_bounds__(256) void dfa_prep_wbt(
    const float* __restrict__ W, unsigned short* __restrict__ Wbt) {
  __shared__ unsigned short tile[64][264];   // [c][d], 33.8 KB
  int t = threadIdx.x;
  int c0 = blockIdx.x * 64;
  int rA = t >> 4;          // 0..15
  int cA = (t & 15) * 4;    // 0..60
#pragma unroll
  for (int p = 0; p < 16; ++p) {
    int r = p * 16 + rA;
    f32x4 v = *(const f32x4*)(W + (size_t)r * C_NCOL + c0 + cA);
    tile[cA + 0][r] = f2bf(v.x);
    tile[cA + 1][r] = f2bf(v.y);
    tile[cA + 2][r] = f2bf(v.z);
    tile[cA + 3][r] = f2bf(v.w);
  }
  __syncthreads();
  int cB = t >> 5;          // 0..7
  int i4 = t & 31;          // 0..31
#pragma unroll
  for (int p = 0; p < 8; ++p) {
    int c = p * 8 + cB;
    int4 o = *(const int4*)&tile[c][i4 * 8];
    *(int4*)(Wbt + (size_t)(c0 + c) * 256 + i4 * 8) = o;
  }
}

// ---------------------------------------------------------------------------
// K1: merged stage-1.
//   blocks [0,300):    logits GEMM via MFMA bf16 from Wbt -> bf16 logits
//   blocks [300,2048): pass-1 linear NCHW f32 -> NCHW fp8 (grid-stride,
//                      fully coalesced both sides; BW-bound ~37us)
// ---------------------------------------------------------------------------
__global__ __launch_bounds__(256) void dfa_stage1(
    const float* __restrict__ fm0, const float* __restrict__ fm1,
    const float* __restrict__ fm2, const float* __restrict__ fm3,
    unsigned char* __restrict__ fm8n,
    const float* __restrict__ IF, const float* __restrict__ AE,
    const unsigned short* __restrict__ Wbt, const float* __restrict__ bwfc,
    unsigned short* __restrict__ logits) {
  __shared__ __align__(16) char smem[20480];
  int id = blockIdx.x;
  int t = threadIdx.x;
  int w = t >> 6, lane = t & 63;

  if (id >= 300) {
    // ---------------- pass-1: linear f32 -> fp8 convert ----------------
    int pid = id - 300;
    for (long long c16 = (long long)pid * 256 + t; c16 < NCH16;
         c16 += 1748ll * 256) {
      long long eb = c16 * 16;       // byte offset in fp8 NCHW space
      const float* src;
      long long off;
      if (eb < LB1)      { src = fm0; off = eb - LB0; }
      else if (eb < LB2) { src = fm1; off = eb - LB1; }
      else if (eb < LB3) { src = fm2; off = eb - LB2; }
      else               { src = fm3; off = eb - LB3; }
      const float* p = src + off;
      f32x4 a0 = *(const f32x4*)(p + 0);
      f32x4 a1 = *(const f32x4*)(p + 4);
      f32x4 a2 = *(const f32x4*)(p + 8);
      f32x4 a3 = *(const f32x4*)(p + 12);
      int4 o;
      o.x = pk_fp8(a0.x, a0.y, a0.z, a0.w);
      o.y = pk_fp8(a1.x, a1.y, a1.z, a1.w);
      o.z = pk_fp8(a2.x, a2.y, a2.z, a2.w);
      o.w = pk_fp8(a3.x, a3.y, a3.z, a3.w);
      *(int4*)(fm8n + eb) = o;
    }
  } else {
    // ---------------- MFMA logits GEMM path ----------------
    typedef unsigned short us40[40];
    us40* As = (us40*)smem;                 // [128][40] = 10240 B
    us40* Bs = (us40*)(smem + 10240);       // [128][40]
    int m0 = (id % 15) * 128;
    int n0 = (id / 15) * 128;

    f32x4v acc[4][4];
#pragma unroll
    for (int mi = 0; mi < 4; ++mi)
#pragma unroll
      for (int ni = 0; ni < 4; ++ni)
        acc[mi][ni] = (f32x4v){0.f, 0.f, 0.f, 0.f};

    int r = t >> 1;              // 0..127 staging row
    int half = (t & 1) * 16;     // elem offset within 32-K slice
    int wr = (w >> 1) * 64, wc = (w & 1) * 64;
    int rsel = lane & 15;
    int koff = (lane >> 4) * 8;

    for (int ks = 0; ks < 8; ++ks) {
      int k0 = ks * 32;
      // A stage: feat = IF+AE, bf16
      {
        int a = m0 + r;
        s16x8 o0 = {0, 0, 0, 0, 0, 0, 0, 0};
        s16x8 o1 = {0, 0, 0, 0, 0, 0, 0, 0};
        if (a < C_NANCH) {
          const float* pI = IF + (size_t)a * 256 + k0 + half;
          const float* pA = AE + (size_t)a * 256 + k0 + half;
          f32x4 i0 = *(const f32x4*)(pI + 0), i1 = *(const f32x4*)(pI + 4);
          f32x4 i2 = *(const f32x4*)(pI + 8), i3 = *(const f32x4*)(pI + 12);
          f32x4 a0 = *(const f32x4*)(pA + 0), a1 = *(const f32x4*)(pA + 4);
          f32x4 a2 = *(const f32x4*)(pA + 8), a3 = *(const f32x4*)(pA + 12);
          o0[0] = (short)f2bf(i0.x + a0.x); o0[1] = (short)f2bf(i0.y + a0.y);
          o0[2] = (short)f2bf(i0.z + a0.z); o0[3] = (short)f2bf(i0.w + a0.w);
          o0[4] = (short)f2bf(i1.x + a1.x); o0[5] = (short)f2bf(i1.y + a1.y);
          o0[6] = (short)f2bf(i1.z + a1.z); o0[7] = (short)f2bf(i1.w + a1.w);
          o1[0] = (short)f2bf(i2.x + a2.x); o1[1] = (short)f2bf(i2.y + a2.y);
          o1[2] = (short)f2bf(i2.z + a2.z); o1[3] = (short)f2bf(i2.w + a2.w);
          o1[4] = (short)f2bf(i3.x + a3.x); o1[5] = (short)f2bf(i3.y + a3.y);
          o1[6] = (short)f2bf(i3.z + a3.z); o1[7] = (short)f2bf(i3.w + a3.w);
        }
        *(s16x8*)&As[r][half] = o0;
        *(s16x8*)&As[r][half + 8] = o1;
      }
      // B stage: Wbt row-major [col][k]
      {
        int c = n0 + r;
        s16x8 b0 = {0, 0, 0, 0, 0, 0, 0, 0};
        s16x8 b1 = {0, 0, 0, 0, 0, 0, 0, 0};
        if (c < C_NCOL) {
          const unsigned short* p = Wbt + (size_t)c * 256 + k0 + half;
          b0 = *(const s16x8*)(p);
          b1 = *(const s16x8*)(p + 8);
        }
        *(s16x8*)&Bs[r][half] = b0;
        *(s16x8*)&Bs[r][half + 8] = b1;
      }
      __syncthreads();

      s16x8 af[4], bf[4];
#pragma unroll
      for (int mi = 0; mi < 4; ++mi)
        af[mi] = *(const s16x8*)&As[wr + mi * 16 + rsel][koff];
#pragma unroll
      for (int ni = 0; ni < 4; ++ni)
        bf[ni] = *(const s16x8*)&Bs[wc + ni * 16 + rsel][koff];
#pragma unroll
      for (int mi = 0; mi < 4; ++mi)
#pragma unroll
        for (int ni = 0; ni < 4; ++ni)
          acc[mi][ni] = __builtin_amdgcn_mfma_f32_16x16x32_bf16(
              af[mi], bf[ni], acc[mi][ni], 0, 0, 0);
      __syncthreads();
    }

    // epilogue: logits(bf16) = acc + bias
    int rowb = (lane >> 4) * 4;
    int colo = lane & 15;
#pragma unroll
    for (int ni = 0; ni < 4; ++ni) {
      int col = n0 + wc + ni * 16 + colo;
      if (col >= C_NCOL) continue;
      float bias = bwfc[col];
#pragma unroll
      for (int mi = 0; mi < 4; ++mi) {
#pragma unroll
        for (int j = 0; j < 4; ++j) {
          int row = m0 + wr + mi * 16 + rowb + j;
          if (row < C_NANCH)
            logits[(size_t)row * C_NCOL + col] = f2bf(acc[mi][ni][j] + bias);
        }
      }
    }
  }
}

// ---------------------------------------------------------------------------
// K2: pass-2 transpose fp8 NCHW -> fp8 NHWC.  256ch x 256px tiles, 708 blocks.
// Strided reads are now 1/4 the bytes (46 MB): dword per channel-row, 4x4
// byte transpose via v_perm, R10's proven full-line phase-B writes.
// ---------------------------------------------------------------------------
__global__ __launch_bounds__(256) void dfa_tr2(
    const unsigned char* __restrict__ fm8n, unsigned char* __restrict__ out) {
  int id = blockIdx.x;
  int HW, strips;
  long long base;
  int rem;
  if (id < 528)      { rem = id;       HW = 11264; strips = 44; base = LB0; }
  else if (id < 660) { rem = id - 528; HW = 2816;  strips = 11; base = LB1; }
  else if (id < 696) { rem = id - 660; HW = 704;   strips = 3;  base = LB2; }
  else               { rem = id - 696; HW = 176;   strips = 1;  base = LB3; }
  int img = rem / strips;
  int px0 = (rem % strips) * 256;

  __shared__ int lds[64][260];     // [chint][px], 66.5 KB
  int t = threadIdx.x;
  int w = t >> 6, lane = t & 63;

  // phase A: dword strided reads + in-register 4x4 byte transpose
  {
    int pxl = lane * 4;
    bool pv = (px0 + pxl) < HW;
    const unsigned char* srcb = fm8n + base + (size_t)img * 256 * HW + px0 + pxl;
    if (pv) {
#pragma unroll 4
      for (int cq = 0; cq < 16; ++cq) {
        int c = w * 64 + cq * 4;
        const unsigned char* s = srcb + (size_t)c * HW;
        unsigned r0 = *(const unsigned*)(s);
        unsigned r1 = *(const unsigned*)(s + HW);
        unsigned r2 = *(const unsigned*)(s + 2 * (size_t)HW);
        unsigned r3 = *(const unsigned*)(s + 3 * (size_t)HW);
        int4 o;
        {
          unsigned tA, tB;
          tA = __builtin_amdgcn_perm(r1, r0, 0x00000400u);
          tB = __builtin_amdgcn_perm(r3, r2, 0x00000400u);
          o.x = (int)__builtin_amdgcn_perm(tB, tA, 0x05040100u);
          tA = __builtin_amdgcn_perm(r1, r0, 0x00000501u);
          tB = __builtin_amdgcn_perm(r3, r2, 0x00000501u);
          o.y = (int)__builtin_amdgcn_perm(tB, tA, 0x05040100u);
          tA = __builtin_amdgcn_perm(r1, r0, 0x00000602u);
          tB = __builtin_amdgcn_perm(r3, r2, 0x00000602u);
          o.z = (int)__builtin_amdgcn_perm(tB, tA, 0x05040100u);
          tA = __builtin_amdgcn_perm(r1, r0, 0x00000703u);
          tB = __builtin_amdgcn_perm(r3, r2, 0x00000703u);
          o.w = (int)__builtin_amdgcn_perm(tB, tA, 0x05040100u);
        }
        *(int4*)&lds[w * 16 + cq][pxl] = o;
      }
    }
  }
  __syncthreads();

  // phase B: gather 256 ch of one px, store 1KB contiguous per wave (R10)
  {
    int cq16 = (lane & 15) * 4;
    int pxs = lane >> 4;
#pragma unroll 4
    for (int i = 0; i < 16; ++i) {
      int px = w * 64 + i * 4 + pxs;
      if (px0 + px < HW) {
        int4 o;
        o.x = lds[cq16 + 0][px];
        o.y = lds[cq16 + 1][px];
        o.z = lds[cq16 + 2][px];
        o.w = lds[cq16 + 3][px];
        *(int4*)(out + base + ((long long)img * HW + px0 + px) * 256 + cq16 * 4) = o;
      }
    }
  }
}

// ---------------------------------------------------------------------------
// K3: fused aggregation (fp8 NHWC ws, bf16 logits).  Block per anchor.
// ---------------------------------------------------------------------------
__global__ __launch_bounds__(256) void dfa_agg_full(
    const unsigned char* __restrict__ fmws,
    const unsigned short* __restrict__ logits,
    const float* __restrict__ IF, const float* __restrict__ anchor,
    const float* __restrict__ Wkps, const float* __restrict__ bkps,
    const float* __restrict__ projm,
    const float* __restrict__ Wout, const float* __restrict__ bout,
    float* __restrict__ out) {
  int bn = blockIdx.x;
  int b = bn / C_NA;
  int t = threadIdx.x;
  int w = t >> 6, lane = t & 63;

  __shared__ __align__(16) float logitsS[8 * 312];    // [g][s]; reused as centry
  __shared__ __align__(16) float swgt[C_NCOL];
  __shared__ unsigned short csS[1248];
  __shared__ __align__(16) float partS[8][256];
  __shared__ __align__(16) float fusedS[256];         // doubles as grid f2[78]
  __shared__ float kpS[13][3];
  __shared__ float invS[8];

  int2* centry = (int2*)logitsS;
  float2* gridS = (float2*)fusedS;

  for (int i = t; i < C_NCOL; i += 256) {
    float v = bf2f(logits[(size_t)bn * C_NCOL + i]);
    logitsS[(i & 7) * 312 + (i >> 3)] = v;
  }
  __syncthreads();

  {
    int g = t >> 5, l32 = t & 31;
    float* row = logitsS + g * 312;
    float m = -1e30f;
    for (int s = l32; s < C_NSLOT; s += 32) m = fmaxf(m, row[s]);
#pragma unroll
    for (int off = 16; off; off >>= 1) m = fmaxf(m, __shfl_xor(m, off, 32));
    float sum = 0.f;
    for (int s = l32; s < C_NSLOT; s += 32) {
      float e = __expf(row[s] - m);
      row[s] = e;
      sum += e;
    }
#pragma unroll
    for (int off = 16; off; off >>= 1) sum += __shfl_xor(sum, off, 32);
    if (l32 == 0) invS[g] = 1.f / sum;
  }
  __syncthreads();

  for (int i = t; i < C_NCOL; i += 256)
    swgt[i] = logitsS[(i & 7) * 312 + (i >> 3)] * invS[i & 7];
  if (t < 39) {
    const float* f = IF + (size_t)bn * 256;
    float a0 = 0.f, a1 = 0.f, a2 = 0.f, a3 = 0.f;
    for (int d = 0; d < 256; d += 4) {
      a0 = fmaf(f[d + 0], Wkps[(d + 0) * 39 + t], a0);
      a1 = fmaf(f[d + 1], Wkps[(d + 1) * 39 + t], a1);
      a2 = fmaf(f[d + 2], Wkps[(d + 2) * 39 + t], a2);
      a3 = fmaf(f[d + 3], Wkps[(d + 3) * 39 + t], a3);
    }
    float acc = bkps[t] + ((a0 + a1) + (a2 + a3));
    int p = t / 3, ax = t % 3;
    kpS[p][ax] = anchor[(size_t)bn * 256 + ax] + acc;
  }
  __syncthreads();

  if (t < 78) {
    int c = t / 13, p = t % 13;
    const float* M = projm + (size_t)(b * 6 + c) * 16;
    float kx = kpS[p][0], ky = kpS[p][1], kz = kpS[p][2];
    float x = M[0] * kx + M[1] * ky + M[2] * kz + M[3];
    float y = M[4] * kx + M[5] * ky + M[6] * kz + M[7];
    float z = M[8] * kx + M[9] * ky + M[10] * kz + M[11];
    float zc = fmaxf(z, 1e-5f);
    float inv = 1.0f / zc;
    gridS[t] = make_float2(x * inv, y * inv);
  }
  __syncthreads();

  int cnt = 0;
  {
    int ebase = w * 312;
#pragma unroll
    for (int r = 0; r < 2; ++r) {
      int li = r * 64 + lane;
      bool lv = li < 78;
      int s = w * 78 + (lv ? li : 0);
      int cam = s / 52, rr = s % 52, l = rr / 13, p = rr % 13;
      float2 g2 = gridS[cam * 13 + p];
      int Wi = (l == 0) ? 176 : (l == 1) ? 88 : (l == 2) ? 44 : 22;
      int Hi = (l == 0) ? 64 : (l == 1) ? 32 : (l == 2) ? 16 : 8;
      float Wf = (float)Wi, Hf = (float)Hi;
      float ix = ((g2.x + 1.0f) * Wf - 1.0f) * 0.5f;
      float iy = ((g2.y + 1.0f) * Hf - 1.0f) * 0.5f;
      float ix0 = floorf(ix), iy0 = floorf(iy);
      float wx1 = ix - ix0, wy1 = iy - iy0;
      float wx0 = 1.f - wx1, wy0 = 1.f - wy1;
      bool vx0 = (ix0 >= 0.f) && (ix0 < Wf);
      bool vx1 = (ix0 + 1.f >= 0.f) && (ix0 + 1.f < Wf);
      bool vy0 = (iy0 >= 0.f) && (iy0 < Hf);
      bool vy1 = (iy0 + 1.f >= 0.f) && (iy0 + 1.f < Hf);
      int xi0 = (int)fminf(fmaxf(ix0, 0.f), Wf - 1.f);
      int xi1 = (int)fminf(fmaxf(ix0 + 1.f, 0.f), Wf - 1.f);
      int yi0 = (int)fminf(fmaxf(iy0, 0.f), Hf - 1.f);
      int yi1 = (int)fminf(fmaxf(iy0 + 1.f, 0.f), Hf - 1.f);
      int lb = (l == 0) ? LB0 : (l == 1) ? LB1 : (l == 2) ? LB2 : LB3;
      int ib = lb + (b * 6 + cam) * Wi * Hi * 256;
      float cw[4];
      int co[4];
      cw[0] = (vx0 && vy0) ? wy0 * wx0 : 0.f;
      cw[1] = (vx1 && vy0) ? wy0 * wx1 : 0.f;
      cw[2] = (vx0 && vy1) ? wy1 * wx0 : 0.f;
      cw[3] = (vx1 && vy1) ? wy1 * wx1 : 0.f;
      co[0] = ib + (yi0 * Wi + xi0) * 256;
      co[1] = ib + (yi0 * Wi + xi1) * 256;
      co[2] = ib + (yi1 * Wi + xi0) * 256;
      co[3] = ib + (yi1 * Wi + xi1) * 256;
      unsigned short sw8 = (unsigned short)(s * 8);
#pragma unroll
      for (int k = 0; k < 4; ++k) {
        bool v = lv && (cw[k] != 0.f);
        unsigned long long mb = __ballot(v);
        int pos = cnt + __popcll(mb & ((1ull << lane) - 1ull));
        if (v) {
          centry[ebase + pos] = make_int2(co[k], __float_as_int(cw[k]));
          csS[ebase + pos] = sw8;
        }
        cnt += (int)__popcll(mb);
      }
    }
    if (cnt & 1) {
      if (lane == 0) {
        centry[ebase + cnt] = make_int2(0, 0);
        csS[ebase + cnt] = 0;
      }
      cnt++;
    }
  }

  int half = lane >> 5, l32 = lane & 31;
  int ch = l32 * 8;
  int g = l32 >> 2;
  float acc[8];
#pragma unroll
  for (int j = 0; j < 8; ++j) acc[j] = 0.f;
  {
    int ebase = w * 312;
    int nIter = cnt >> 1;
#pragma unroll 8
    for (int i = 0; i < nIter; ++i) {
      int idx = ebase + 2 * i + half;
      int2 e = centry[idx];
      float wgt_s = swgt[(int)csS[idx] + g];
      float cw = __int_as_float(e.y) * wgt_s;
      int2 u = *reinterpret_cast<const int2*>(fmws + e.x + ch);
      floatx2 p0 = __builtin_amdgcn_cvt_pk_f32_fp8(u.x, false);
      floatx2 p1 = __builtin_amdgcn_cvt_pk_f32_fp8(u.x, true);
      floatx2 p2 = __builtin_amdgcn_cvt_pk_f32_fp8(u.y, false);
      floatx2 p3 = __builtin_amdgcn_cvt_pk_f32_fp8(u.y, true);
      acc[0] = fmaf(cw, p0.x, acc[0]);
      acc[1] = fmaf(cw, p0.y, acc[1]);
      acc[2] = fmaf(cw, p1.x, acc[2]);
      acc[3] = fmaf(cw, p1.y, acc[3]);
      acc[4] = fmaf(cw, p2.x, acc[4]);
      acc[5] = fmaf(cw, p2.y, acc[5]);
      acc[6] = fmaf(cw, p3.x, acc[6]);
      acc[7] = fmaf(cw, p3.y, acc[7]);
    }
  }
  {
    int row = w * 2 + half;
    float4 v0 = make_float4(acc[0], acc[1], acc[2], acc[3]);
    float4 v1 = make_float4(acc[4], acc[5], acc[6], acc[7]);
    *reinterpret_cast<float4*>(&partS[row][ch]) = v0;
    *reinterpret_cast<float4*>(&partS[row][ch + 4]) = v1;
  }
  __syncthreads();

  float fv = 0.f;
#pragma unroll
  for (int r = 0; r < 8; ++r) fv += partS[r][t];
  fusedS[t] = fv;
  __syncthreads();

  float o = bout[t] + IF[(size_t)bn * 256 + t];
#pragma unroll 8
  for (int d = 0; d < 256; ++d)
    o = fmaf(fusedS[d], Wout[d * 256 + t], o);
  out[(size_t)bn * 256 + t] = o;
}

// ---------------------------------------------------------------------------
// Fallback path (small ws): f32 logits GEMM + softmax + points + NCHW agg
// ---------------------------------------------------------------------------
__global__ __launch_bounds__(256) void dfa_logits_gemm_fb(
    const float* __restrict__ IF, const float* __restrict__ AE,
    const float* __restrict__ Wwfc, const float* __restrict__ bwfc,
    float* __restrict__ logits) {
  __shared__ float feat_t[256][16];
  int t = threadIdx.x;
  int a0 = blockIdx.x * 15;
  int col = blockIdx.y * 256 + t;
  bool cv = col < C_NCOL;
#pragma unroll
  for (int a = 0; a < 15; ++a) {
    int bn = a0 + a;
    feat_t[t][a] = IF[(size_t)bn * 256 + t] + AE[(size_t)bn * 256 + t];
  }
  feat_t[t][15] = 0.f;
  __syncthreads();
  float acc[15];
  float bias = cv ? bwfc[col] : 0.f;
#pragma unroll
  for (int a = 0; a < 15; ++a) acc[a] = bias;
  const float* wp = Wwfc + col;
#pragma unroll 8
  for (int d = 0; d < 256; ++d) {
    float wv = cv ? wp[(size_t)d * C_NCOL] : 0.f;
#pragma unroll
    for (int a = 0; a < 15; ++a) acc[a] = fmaf(feat_t[d][a], wv, acc[a]);
  }
  if (cv) {
#pragma unroll
    for (int a = 0; a < 15; ++a)
      logits[(size_t)(a0 + a) * C_NCOL + col] = acc[a];
  }
}

__global__ __launch_bounds__(256) void dfa_softmax(float* __restrict__ wgt) {
  int bn = blockIdx.x;
  float* w = wgt + (size_t)bn * C_NCOL;
  __shared__ float buf[C_NCOL];
  int t = threadIdx.x;
  for (int i = t; i < C_NCOL; i += 256) buf[i] = w[i];
  __syncthreads();
  int g = t >> 5, lane = t & 31;
  float m = -1e30f;
  for (int s = lane; s < C_NSLOT; s += 32) m = fmaxf(m, buf[s * 8 + g]);
#pragma unroll
  for (int off = 16; off; off >>= 1) m = fmaxf(m, __shfl_xor(m, off, 32));
  float sum = 0.f;
  for (int s = lane; s < C_NSLOT; s += 32) {
    float e = expf(buf[s * 8 + g] - m);
    buf[s * 8 + g] = e;
    sum += e;
  }
#pragma unroll
  for (int off = 16; off; off >>= 1) sum += __shfl_xor(sum, off, 32);
  float inv = 1.f / sum;
  for (int s = lane; s < C_NSLOT; s += 32) w[s * 8 + g] = buf[s * 8 + g] * inv;
}

__global__ __launch_bounds__(128) void dfa_points(
    const float* __restrict__ IF, const float* __restrict__ anchor,
    const float* __restrict__ Wkps, const float* __restrict__ bkps,
    const float* __restrict__ projm, float2* __restrict__ grid) {
  int bn = blockIdx.x;
  int b = bn / C_NA;
  int t = threadIdx.x;
  __shared__ float kp[13][3];
  if (t < 39) {
    float acc = bkps[t];
    const float* f = IF + (size_t)bn * 256;
    for (int d = 0; d < 256; ++d) acc = fmaf(f[d], Wkps[d * 39 + t], acc);
    int p = t / 3, ax = t % 3;
    kp[p][ax] = anchor[(size_t)bn * 256 + ax] + acc;
  }
  __syncthreads();
  if (t < 78) {
    int c = t / 13, p = t % 13;
    const float* M = projm + (size_t)(b * 6 + c) * 16;
    float kx = kp[p][0], ky = kp[p][1], kz = kp[p][2];
    float x = M[0] * kx + M[1] * ky + M[2] * kz + M[3];
    float y = M[4] * kx + M[5] * ky + M[6] * kz + M[7];
    float z = M[8] * kx + M[9] * ky + M[10] * kz + M[11];
    float zc = fmaxf(z, 1e-5f);
    float inv = 1.0f / zc;
    grid[(size_t)bn * 78 + t] = make_float2(x * inv, y * inv);
  }
}

struct __align__(16) SlotInfo { int o[4]; float w[4]; };

__global__ __launch_bounds__(256) void dfa_agg_fb(
    const float* __restrict__ fm0, const float* __restrict__ fm1,
    const float* __restrict__ fm2, const float* __restrict__ fm3,
    const float2* __restrict__ grid, const float* __restrict__ wgt,
    const float* __restrict__ IF, const float* __restrict__ Wout,
    const float* __restrict__ bout, float* __restrict__ out) {
  int bn = blockIdx.x;
  int b = bn / C_NA;
  int t = threadIdx.x;
  int w = t >> 6, lane = t & 63;

  __shared__ SlotInfo slot[C_NSLOT];
  __shared__ int sflag[C_NSLOT];
  __shared__ float swgt[C_NCOL];
  __shared__ float part[4][256];
  __shared__ float fused[256];

  for (int i = t; i < C_NCOL; i += 256) swgt[i] = wgt[(size_t)bn * C_NCOL + i];

  for (int s = t; s < C_NSLOT; s += 256) {
    int c = s / 52, r = s % 52, l = r / 13, p = r % 13;
    float2 g2 = grid[(size_t)bn * 78 + c * 13 + p];
    int Wi = (l == 0) ? 176 : (l == 1) ? 88 : (l == 2) ? 44 : 22;
    int Hi = (l == 0) ? 64 : (l == 1) ? 32 : (l == 2) ? 16 : 8;
    float Wf = (float)Wi, Hf = (float)Hi;
    float ix = ((g2.x + 1.0f) * Wf - 1.0f) * 0.5f;
    float iy = ((g2.y + 1.0f) * Hf - 1.0f) * 0.5f;
    float ix0 = floorf(ix), iy0 = floorf(iy);
    float wx1 = ix - ix0, wy1 = iy - iy0;
    float wx0 = 1.f - wx1, wy0 = 1.f - wy1;
    bool vx0 = (ix0 >= 0.f) && (ix0 < Wf);
    bool vx1 = (ix0 + 1.f >= 0.f) && (ix0 + 1.f < Wf);
    bool vy0 = (iy0 >= 0.f) && (iy0 < Hf);
    bool vy1 = (iy0 + 1.f >= 0.f) && (iy0 + 1.f < Hf);
    int xi0 = (int)fminf(fmaxf(ix0, 0.f), Wf - 1.f);
    int xi1 = (int)fminf(fmaxf(ix0 + 1.f, 0.f), Wf - 1.f);
    int yi0 = (int)fminf(fmaxf(iy0, 0.f), Hf - 1.f);
    int yi1 = (int)fminf(fmaxf(iy0 + 1.f, 0.f), Hf - 1.f);
    int img = b * 6 + c;
    int HW = Wi * Hi;
    SlotInfo si;
    int ib = img * 256 * HW;
    si.o[0] = ib + yi0 * Wi + xi0;
    si.o[1] = ib + yi0 * Wi + xi1;
    si.o[2] = ib + yi1 * Wi + xi0;
    si.o[3] = ib + yi1 * Wi + xi1;
    si.w[0] = (vx0 && vy0) ? wy0 * wx0 : 0.f;
    si.w[1] = (vx1 && vy0) ? wy0 * wx1 : 0.f;
    si.w[2] = (vx0 && vy1) ? wy1 * wx0 : 0.f;
    si.w[3] = (vx1 && vy1) ? wy1 * wx1 : 0.f;
    slot[s] = si;
    sflag[s] = (si.w[0] + si.w[1] + si.w[2] + si.w[3] == 0.f) ? -1 : l;
  }
  __syncthreads();

  int g = lane >> 3;
  int ch = lane * 4;
  float4 acc = make_float4(0.f, 0.f, 0.f, 0.f);
  for (int s = w; s < C_NSLOT; s += 4) {
    int fl = sflag[s];
    if (fl < 0) continue;
    SlotInfo si = slot[s];
    float wg = swgt[s * 8 + g];
    const float* fp = (fl == 0) ? fm0 : (fl == 1) ? fm1 : (fl == 2) ? fm2 : fm3;
    int HW = (fl == 0) ? 11264 : (fl == 1) ? 2816 : (fl == 2) ? 704 : 176;
    float4 sv = make_float4(0.f, 0.f, 0.f, 0.f);
#pragma unroll
    for (int k = 0; k < 4; ++k) {
      if (si.w[k] != 0.f) {
        sv.x = fmaf(si.w[k], fp[si.o[k] + (size_t)(ch + 0) * HW], sv.x);
        sv.y = fmaf(si.w[k], fp[si.o[k] + (size_t)(ch + 1) * HW], sv.y);
        sv.z = fmaf(si.w[k], fp[si.o[k] + (size_t)(ch + 2) * HW], sv.z);
        sv.w = fmaf(si.w[k], fp[si.o[k] + (size_t)(ch + 3) * HW], sv.w);
      }
    }
    acc.x = fmaf(sv.x, wg, acc.x);
    acc.y = fmaf(sv.y, wg, acc.y);
    acc.z = fmaf(sv.z, wg, acc.z);
    acc.w = fmaf(sv.w, wg, acc.w);
  }
  *reinterpret_cast<float4*>(&part[w][ch]) = acc;
  __syncthreads();

  fused[t] = part[0][t] + part[1][t] + part[2][t] + part[3][t];
  __syncthreads();

  float o = bout[t] + IF[(size_t)bn * 256 + t];
#pragma unroll 4
  for (int d = 0; d < 256; ++d)
    o = fmaf(fused[d], Wout[d * 256 + t], o);
  out[(size_t)bn * 256 + t] = o;
}

// ---------------------------------------------------------------------------
extern "C" void kernel_launch(void* const* d_in, const int* in_sizes, int n_in,
                              void* d_out, int out_size, void* d_ws, size_t ws_size,
                              hipStream_t stream) {
  const float* IF     = (const float*)d_in[0];
  const float* anchor = (const float*)d_in[1];
  const float* AE     = (const float*)d_in[2];
  const float* fm0    = (const float*)d_in[3];
  const float* fm1    = (const float*)d_in[4];
  const float* fm2    = (const float*)d_in[5];
  const float* fm3    = (const float*)d_in[6];
  const float* projm  = (const float*)d_in[7];
  const float* Wkps   = (const float*)d_in[8];
  const float* bkps   = (const float*)d_in[9];
  const float* Wwfc   = (const float*)d_in[10];
  const float* bwfc   = (const float*)d_in[11];
  const float* Wout   = (const float*)d_in[12];
  const float* bout   = (const float*)d_in[13];
  float* out = (float*)d_out;
  char* ws = (char*)d_ws;

  bool full = ws_size >= (2 * FM8_WS_BYTES + WGT16_WS_BYTES + WBT_WS_BYTES);
  if (full) {
    unsigned char* fmws = (unsigned char*)ws;                       // NHWC fp8
    unsigned char* fm8n = (unsigned char*)(ws + FM8_WS_BYTES);      // NCHW fp8
    unsigned short* wgt16 = (unsigned short*)(ws + 2 * FM8_WS_BYTES);
    unsigned short* wbt = (unsigned short*)(ws + 2 * FM8_WS_BYTES + WGT16_WS_BYTES);
    dfa_prep_wbt<<<39, 256, 0, stream>>>(Wwfc, wbt);
    dfa_stage1<<<2048, 256, 0, stream>>>(fm0, fm1, fm2, fm3, fm8n,
                                         IF, AE, wbt, bwfc, wgt16);
    dfa_tr2<<<708, 256, 0, stream>>>(fm8n, fmws);
    dfa_agg_full<<<1800, 256, 0, stream>>>(fmws, wgt16, IF, anchor, Wkps, bkps,
                                           projm, Wout, bout, out);
  } else {
    float* wgt  = (float*)ws;
    float2* grd = (float2*)(ws + 17971200ull);
    dfa_logits_gemm_fb<<<dim3(120, 10), 256, 0, stream>>>(IF, AE, Wwfc, bwfc, wgt);
    dfa_softmax<<<1800, 256, 0, stream>>>(wgt);
    dfa_points<<<1800, 128, 0, stream>>>(IF, anchor, Wkps, bkps, projm, grd);
    dfa_agg_fb<<<1800, 256, 0, stream>>>(fm0, fm1, fm2, fm3, grd, wgt,
                                         IF, Wout, bout, out);
  }
}

// Round 18
// 119.406 us; speedup vs baseline: 1.1673x; 1.1673x over previous
//
#include <hip/hip_runtime.h>
#include <hip/hip_bf16.h>

// Problem constants
#define C_NUM_CAMS 6
#define C_NUM_LEVELS 4
#define C_NUM_PTS 13
#define C_NUM_GROUPS 8
#define C_BS 2
#define C_NA 900
#define C_E 256
#define C_NSLOT 312      // C*L*P
#define C_NCOL 2496      // NSLOT * G
#define C_NANCH 1800     // BS*NA

// Level geometry: H 64,32,16,8; W 176,88,44,22; HW 11264,2816,704,176
// fp8 ws: 1 byte/elem, bases in bytes
#define LB0 0
#define LB1 34603008     // 12*11264*256
#define LB2 43253760     // +12*2816*256
#define LB3 45416448     // +12*704*256
#define FM8_WS_BYTES 45957120ull
#define WGT16_WS_BYTES 8985600ull  // 1800*2496*2 (bf16 logits)
#define WBT_WS_BYTES 1277952ull    // 2496*256*2

typedef float floatx2 __attribute__((ext_vector_type(2)));
typedef float f32x4 __attribute__((ext_vector_type(4)));
typedef short s16x8 __attribute__((ext_vector_type(8)));
typedef float f32x4v __attribute__((ext_vector_type(4)));

static __device__ __forceinline__ int pk_fp8(float a, float b, float c, float d) {
  int v = __builtin_amdgcn_cvt_pk_fp8_f32(a, b, 0, false);   // bytes 0,1
  v = __builtin_amdgcn_cvt_pk_fp8_f32(c, d, v, true);        // bytes 2,3
  return v;
}
static __device__ __forceinline__ unsigned short f2bf(float f) {
  __hip_bfloat16 h = __float2bfloat16(f);
  return *reinterpret_cast<unsigned short*>(&h);
}
static __device__ __forceinline__ float bf2f(unsigned short u) {
  unsigned int v = ((unsigned int)u) << 16;
  float f;
  __builtin_memcpy(&f, &v, 4);
  return f;
}

// ---------------------------------------------------------------------------
// K0: prep — coalesced transpose Wwfc f32[256][2496] -> Wbt bf16[2496][256].
// ---------------------------------------------------------------------------
__global__ __launch_bounds__(256) void dfa_prep_wbt(
    const float* __restrict__ W, unsigned short* __restrict__ Wbt) {
  __shared__ unsigned short tile[64][264];   // [c][d], 33.8 KB
  int t = threadIdx.x;
  int c0 = blockIdx.x * 64;
  int rA = t >> 4;          // 0..15
  int cA = (t & 15) * 4;    // 0..60
#pragma unroll
  for (int p = 0; p < 16; ++p) {
    int r = p * 16 + rA;
    f32x4 v = *(const f32x4*)(W + (size_t)r * C_NCOL + c0 + cA);
    tile[cA + 0][r] = f2bf(v.x);
    tile[cA + 1][r] = f2bf(v.y);
    tile[cA + 2][r] = f2bf(v.z);
    tile[cA + 3][r] = f2bf(v.w);
  }
  __syncthreads();
  int cB = t >> 5;          // 0..7
  int i4 = t & 31;          // 0..31
#pragma unroll
  for (int p = 0; p < 8; ++p) {
    int c = p * 8 + cB;
    int4 o = *(const int4*)&tile[c][i4 * 8];
    *(int4*)(Wbt + (size_t)(c0 + c) * 256 + i4 * 8) = o;
  }
}

// ---------------------------------------------------------------------------
// K1: merged stage-1 (R16 structure, bf16 logits).
//   blocks [0,300):   logits GEMM via MFMA bf16 from Wbt -> bf16 logits
//   blocks [300,1008): NCHW f32 -> NHWC fp8 transpose (input-ingest wall)
// ---------------------------------------------------------------------------
__global__ __launch_bounds__(256) void dfa_stage1(
    const float* __restrict__ fm0, const float* __restrict__ fm1,
    const float* __restrict__ fm2, const float* __restrict__ fm3,
    unsigned char* __restrict__ outw,
    const float* __restrict__ IF, const float* __restrict__ AE,
    const unsigned short* __restrict__ Wbt, const float* __restrict__ bwfc,
    unsigned short* __restrict__ logits) {
  __shared__ __align__(16) char smem[66560];
  int id = blockIdx.x;
  int t = threadIdx.x;
  int w = t >> 6, lane = t & 63;

  if (id >= 300) {
    // ---------------- transpose path (R10/R16 body) ----------------
    int tid = id - 300;
    int (*lds)[260] = (int(*)[260])smem;
    const float* fm;
    int HW, strips;
    long long base;
    int rem;
    if (tid < 528)      { rem = tid;       fm = fm0; HW = 11264; strips = 44; base = LB0; }
    else if (tid < 660) { rem = tid - 528; fm = fm1; HW = 2816;  strips = 11; base = LB1; }
    else if (tid < 696) { rem = tid - 660; fm = fm2; HW = 704;   strips = 3;  base = LB2; }
    else                { rem = tid - 696; fm = fm3; HW = 176;   strips = 1;  base = LB3; }
    int img = rem / strips;
    int px0 = (rem % strips) * 256;

    {
      int pxl = lane * 4;
      bool pv = (px0 + pxl) < HW;
      const float* src = fm + (size_t)img * 256 * HW + px0 + pxl;
      if (pv) {
#pragma unroll 4
        for (int cq = 0; cq < 16; ++cq) {
          int ch = w * 64 + cq * 4;
          const float* s = src + (size_t)ch * HW;
          f32x4 r0 = *(const f32x4*)(s);
          f32x4 r1 = *(const f32x4*)(s + HW);
          f32x4 r2 = *(const f32x4*)(s + 2 * (size_t)HW);
          f32x4 r3 = *(const f32x4*)(s + 3 * (size_t)HW);
          int4 o;
          o.x = pk_fp8(r0.x, r1.x, r2.x, r3.x);
          o.y = pk_fp8(r0.y, r1.y, r2.y, r3.y);
          o.z = pk_fp8(r0.z, r1.z, r2.z, r3.z);
          o.w = pk_fp8(r0.w, r1.w, r2.w, r3.w);
          *(int4*)&lds[w * 16 + cq][pxl] = o;
        }
      }
    }
    __syncthreads();
    {
      int cq16 = (lane & 15) * 4;
      int pxs = lane >> 4;
#pragma unroll 4
      for (int i = 0; i < 16; ++i) {
        int px = w * 64 + i * 4 + pxs;
        if (px0 + px < HW) {
          int4 o;
          o.x = lds[cq16 + 0][px];
          o.y = lds[cq16 + 1][px];
          o.z = lds[cq16 + 2][px];
          o.w = lds[cq16 + 3][px];
          *(int4*)(outw + base + ((long long)img * HW + px0 + px) * 256 + cq16 * 4) = o;
        }
      }
    }
  } else {
    // ---------------- MFMA logits GEMM path ----------------
    typedef unsigned short us40[40];
    us40* As = (us40*)smem;                 // [128][40] = 10240 B
    us40* Bs = (us40*)(smem + 10240);       // [128][40]
    int m0 = (id % 15) * 128;
    int n0 = (id / 15) * 128;

    f32x4v acc[4][4];
#pragma unroll
    for (int mi = 0; mi < 4; ++mi)
#pragma unroll
      for (int ni = 0; ni < 4; ++ni)
        acc[mi][ni] = (f32x4v){0.f, 0.f, 0.f, 0.f};

    int r = t >> 1;              // 0..127 staging row
    int half = (t & 1) * 16;     // elem offset within 32-K slice
    int wr = (w >> 1) * 64, wc = (w & 1) * 64;
    int rsel = lane & 15;
    int koff = (lane >> 4) * 8;

    for (int ks = 0; ks < 8; ++ks) {
      int k0 = ks * 32;
      // A stage: feat = IF+AE, bf16
      {
        int a = m0 + r;
        s16x8 o0 = {0, 0, 0, 0, 0, 0, 0, 0};
        s16x8 o1 = {0, 0, 0, 0, 0, 0, 0, 0};
        if (a < C_NANCH) {
          const float* pI = IF + (size_t)a * 256 + k0 + half;
          const float* pA = AE + (size_t)a * 256 + k0 + half;
          f32x4 i0 = *(const f32x4*)(pI + 0), i1 = *(const f32x4*)(pI + 4);
          f32x4 i2 = *(const f32x4*)(pI + 8), i3 = *(const f32x4*)(pI + 12);
          f32x4 a0 = *(const f32x4*)(pA + 0), a1 = *(const f32x4*)(pA + 4);
          f32x4 a2 = *(const f32x4*)(pA + 8), a3 = *(const f32x4*)(pA + 12);
          o0[0] = (short)f2bf(i0.x + a0.x); o0[1] = (short)f2bf(i0.y + a0.y);
          o0[2] = (short)f2bf(i0.z + a0.z); o0[3] = (short)f2bf(i0.w + a0.w);
          o0[4] = (short)f2bf(i1.x + a1.x); o0[5] = (short)f2bf(i1.y + a1.y);
          o0[6] = (short)f2bf(i1.z + a1.z); o0[7] = (short)f2bf(i1.w + a1.w);
          o1[0] = (short)f2bf(i2.x + a2.x); o1[1] = (short)f2bf(i2.y + a2.y);
          o1[2] = (short)f2bf(i2.z + a2.z); o1[3] = (short)f2bf(i2.w + a2.w);
          o1[4] = (short)f2bf(i3.x + a3.x); o1[5] = (short)f2bf(i3.y + a3.y);
          o1[6] = (short)f2bf(i3.z + a3.z); o1[7] = (short)f2bf(i3.w + a3.w);
        }
        *(s16x8*)&As[r][half] = o0;
        *(s16x8*)&As[r][half + 8] = o1;
      }
      // B stage: Wbt row-major [col][k]
      {
        int c = n0 + r;
        s16x8 b0 = {0, 0, 0, 0, 0, 0, 0, 0};
        s16x8 b1 = {0, 0, 0, 0, 0, 0, 0, 0};
        if (c < C_NCOL) {
          const unsigned short* p = Wbt + (size_t)c * 256 + k0 + half;
          b0 = *(const s16x8*)(p);
          b1 = *(const s16x8*)(p + 8);
        }
        *(s16x8*)&Bs[r][half] = b0;
        *(s16x8*)&Bs[r][half + 8] = b1;
      }
      __syncthreads();

      s16x8 af[4], bf[4];
#pragma unroll
      for (int mi = 0; mi < 4; ++mi)
        af[mi] = *(const s16x8*)&As[wr + mi * 16 + rsel][koff];
#pragma unroll
      for (int ni = 0; ni < 4; ++ni)
        bf[ni] = *(const s16x8*)&Bs[wc + ni * 16 + rsel][koff];
#pragma unroll
      for (int mi = 0; mi < 4; ++mi)
#pragma unroll
        for (int ni = 0; ni < 4; ++ni)
          acc[mi][ni] = __builtin_amdgcn_mfma_f32_16x16x32_bf16(
              af[mi], bf[ni], acc[mi][ni], 0, 0, 0);
      __syncthreads();
    }

    // epilogue: logits(bf16) = acc + bias
    int rowb = (lane >> 4) * 4;
    int colo = lane & 15;
#pragma unroll
    for (int ni = 0; ni < 4; ++ni) {
      int col = n0 + wc + ni * 16 + colo;
      if (col >= C_NCOL) continue;
      float bias = bwfc[col];
#pragma unroll
      for (int mi = 0; mi < 4; ++mi) {
#pragma unroll
        for (int j = 0; j < 4; ++j) {
          int row = m0 + wr + mi * 16 + rowb + j;
          if (row < C_NANCH)
            logits[(size_t)row * C_NCOL + col] = f2bf(acc[mi][ni][j] + bias);
        }
      }
    }
  }
}

// ---------------------------------------------------------------------------
// K3: fused aggregation (fp8 NHWC ws, bf16 logits).  Block per anchor.
// ---------------------------------------------------------------------------
__global__ __launch_bounds__(256) void dfa_agg_full(
    const unsigned char* __restrict__ fmws,
    const unsigned short* __restrict__ logits,
    const float* __restrict__ IF, const float* __restrict__ anchor,
    const float* __restrict__ Wkps, const float* __restrict__ bkps,
    const float* __restrict__ projm,
    const float* __restrict__ Wout, const float* __restrict__ bout,
    float* __restrict__ out) {
  int bn = blockIdx.x;
  int b = bn / C_NA;
  int t = threadIdx.x;
  int w = t >> 6, lane = t & 63;

  __shared__ __align__(16) float logitsS[8 * 312];    // [g][s]; reused as centry
  __shared__ __align__(16) float swgt[C_NCOL];
  __shared__ unsigned short csS[1248];
  __shared__ __align__(16) float partS[8][256];
  __shared__ __align__(16) float fusedS[256];         // doubles as grid f2[78]
  __shared__ float kpS[13][3];
  __shared__ float invS[8];

  int2* centry = (int2*)logitsS;
  float2* gridS = (float2*)fusedS;

  for (int i = t; i < C_NCOL; i += 256) {
    float v = bf2f(logits[(size_t)bn * C_NCOL + i]);
    logitsS[(i & 7) * 312 + (i >> 3)] = v;
  }
  __syncthreads();

  {
    int g = t >> 5, l32 = t & 31;
    float* row = logitsS + g * 312;
    float m = -1e30f;
    for (int s = l32; s < C_NSLOT; s += 32) m = fmaxf(m, row[s]);
#pragma unroll
    for (int off = 16; off; off >>= 1) m = fmaxf(m, __shfl_xor(m, off, 32));
    float sum = 0.f;
    for (int s = l32; s < C_NSLOT; s += 32) {
      float e = __expf(row[s] - m);
      row[s] = e;
      sum += e;
    }
#pragma unroll
    for (int off = 16; off; off >>= 1) sum += __shfl_xor(sum, off, 32);
    if (l32 == 0) invS[g] = 1.f / sum;
  }
  __syncthreads();

  for (int i = t; i < C_NCOL; i += 256)
    swgt[i] = logitsS[(i & 7) * 312 + (i >> 3)] * invS[i & 7];
  if (t < 39) {
    const float* f = IF + (size_t)bn * 256;
    float a0 = 0.f, a1 = 0.f, a2 = 0.f, a3 = 0.f;
    for (int d = 0; d < 256; d += 4) {
      a0 = fmaf(f[d + 0], Wkps[(d + 0) * 39 + t], a0);
      a1 = fmaf(f[d + 1], Wkps[(d + 1) * 39 + t], a1);
      a2 = fmaf(f[d + 2], Wkps[(d + 2) * 39 + t], a2);
      a3 = fmaf(f[d + 3], Wkps[(d + 3) * 39 + t], a3);
    }
    float acc = bkps[t] + ((a0 + a1) + (a2 + a3));
    int p = t / 3, ax = t % 3;
    kpS[p][ax] = anchor[(size_t)bn * 256 + ax] + acc;
  }
  __syncthreads();

  if (t < 78) {
    int c = t / 13, p = t % 13;
    const float* M = projm + (size_t)(b * 6 + c) * 16;
    float kx = kpS[p][0], ky = kpS[p][1], kz = kpS[p][2];
    float x = M[0] * kx + M[1] * ky + M[2] * kz + M[3];
    float y = M[4] * kx + M[5] * ky + M[6] * kz + M[7];
    float z = M[8] * kx + M[9] * ky + M[10] * kz + M[11];
    float zc = fmaxf(z, 1e-5f);
    float inv = 1.0f / zc;
    gridS[t] = make_float2(x * inv, y * inv);
  }
  __syncthreads();

  int cnt = 0;
  {
    int ebase = w * 312;
#pragma unroll
    for (int r = 0; r < 2; ++r) {
      int li = r * 64 + lane;
      bool lv = li < 78;
      int s = w * 78 + (lv ? li : 0);
      int cam = s / 52, rr = s % 52, l = rr / 13, p = rr % 13;
      float2 g2 = gridS[cam * 13 + p];
      int Wi = (l == 0) ? 176 : (l == 1) ? 88 : (l == 2) ? 44 : 22;
      int Hi = (l == 0) ? 64 : (l == 1) ? 32 : (l == 2) ? 16 : 8;
      float Wf = (float)Wi, Hf = (float)Hi;
      float ix = ((g2.x + 1.0f) * Wf - 1.0f) * 0.5f;
      float iy = ((g2.y + 1.0f) * Hf - 1.0f) * 0.5f;
      float ix0 = floorf(ix), iy0 = floorf(iy);
      float wx1 = ix - ix0, wy1 = iy - iy0;
      float wx0 = 1.f - wx1, wy0 = 1.f - wy1;
      bool vx0 = (ix0 >= 0.f) && (ix0 < Wf);
      bool vx1 = (ix0 + 1.f >= 0.f) && (ix0 + 1.f < Wf);
      bool vy0 = (iy0 >= 0.f) && (iy0 < Hf);
      bool vy1 = (iy0 + 1.f >= 0.f) && (iy0 + 1.f < Hf);
      int xi0 = (int)fminf(fmaxf(ix0, 0.f), Wf - 1.f);
      int xi1 = (int)fminf(fmaxf(ix0 + 1.f, 0.f), Wf - 1.f);
      int yi0 = (int)fminf(fmaxf(iy0, 0.f), Hf - 1.f);
      int yi1 = (int)fminf(fmaxf(iy0 + 1.f, 0.f), Hf - 1.f);
      int lb = (l == 0) ? LB0 : (l == 1) ? LB1 : (l == 2) ? LB2 : LB3;
      int ib = lb + (b * 6 + cam) * Wi * Hi * 256;
      float cw[4];
      int co[4];
      cw[0] = (vx0 && vy0) ? wy0 * wx0 : 0.f;
      cw[1] = (vx1 && vy0) ? wy0 * wx1 : 0.f;
      cw[2] = (vx0 && vy1) ? wy1 * wx0 : 0.f;
      cw[3] = (vx1 && vy1) ? wy1 * wx1 : 0.f;
      co[0] = ib + (yi0 * Wi + xi0) * 256;
      co[1] = ib + (yi0 * Wi + xi1) * 256;
      co[2] = ib + (yi1 * Wi + xi0) * 256;
      co[3] = ib + (yi1 * Wi + xi1) * 256;
      unsigned short sw8 = (unsigned short)(s * 8);
#pragma unroll
      for (int k = 0; k < 4; ++k) {
        bool v = lv && (cw[k] != 0.f);
        unsigned long long mb = __ballot(v);
        int pos = cnt + __popcll(mb & ((1ull << lane) - 1ull));
        if (v) {
          centry[ebase + pos] = make_int2(co[k], __float_as_int(cw[k]));
          csS[ebase + pos] = sw8;
        }
        cnt += (int)__popcll(mb);
      }
    }
    if (cnt & 1) {
      if (lane == 0) {
        centry[ebase + cnt] = make_int2(0, 0);
        csS[ebase + cnt] = 0;
      }
      cnt++;
    }
  }

  int half = lane >> 5, l32 = lane & 31;
  int ch = l32 * 8;
  int g = l32 >> 2;
  float acc[8];
#pragma unroll
  for (int j = 0; j < 8; ++j) acc[j] = 0.f;
  {
    int ebase = w * 312;
    int nIter = cnt >> 1;
#pragma unroll 8
    for (int i = 0; i < nIter; ++i) {
      int idx = ebase + 2 * i + half;
      int2 e = centry[idx];
      float wgt_s = swgt[(int)csS[idx] + g];
      float cw = __int_as_float(e.y) * wgt_s;
      int2 u = *reinterpret_cast<const int2*>(fmws + e.x + ch);
      floatx2 p0 = __builtin_amdgcn_cvt_pk_f32_fp8(u.x, false);
      floatx2 p1 = __builtin_amdgcn_cvt_pk_f32_fp8(u.x, true);
      floatx2 p2 = __builtin_amdgcn_cvt_pk_f32_fp8(u.y, false);
      floatx2 p3 = __builtin_amdgcn_cvt_pk_f32_fp8(u.y, true);
      acc[0] = fmaf(cw, p0.x, acc[0]);
      acc[1] = fmaf(cw, p0.y, acc[1]);
      acc[2] = fmaf(cw, p1.x, acc[2]);
      acc[3] = fmaf(cw, p1.y, acc[3]);
      acc[4] = fmaf(cw, p2.x, acc[4]);
      acc[5] = fmaf(cw, p2.y, acc[5]);
      acc[6] = fmaf(cw, p3.x, acc[6]);
      acc[7] = fmaf(cw, p3.y, acc[7]);
    }
  }
  {
    int row = w * 2 + half;
    float4 v0 = make_float4(acc[0], acc[1], acc[2], acc[3]);
    float4 v1 = make_float4(acc[4], acc[5], acc[6], acc[7]);
    *reinterpret_cast<float4*>(&partS[row][ch]) = v0;
    *reinterpret_cast<float4*>(&partS[row][ch + 4]) = v1;
  }
  __syncthreads();

  float fv = 0.f;
#pragma unroll
  for (int r = 0; r < 8; ++r) fv += partS[r][t];
  fusedS[t] = fv;
  __syncthreads();

  float o = bout[t] + IF[(size_t)bn * 256 + t];
#pragma unroll 8
  for (int d = 0; d < 256; ++d)
    o = fmaf(fusedS[d], Wout[d * 256 + t], o);
  out[(size_t)bn * 256 + t] = o;
}

// ---------------------------------------------------------------------------
// Fallback path (small ws): f32 logits GEMM + softmax + points + NCHW agg
// ---------------------------------------------------------------------------
__global__ __launch_bounds__(256) void dfa_logits_gemm_fb(
    const float* __restrict__ IF, const float* __restrict__ AE,
    const float* __restrict__ Wwfc, const float* __restrict__ bwfc,
    float* __restrict__ logits) {
  __shared__ float feat_t[256][16];
  int t = threadIdx.x;
  int a0 = blockIdx.x * 15;
  int col = blockIdx.y * 256 + t;
  bool cv = col < C_NCOL;
#pragma unroll
  for (int a = 0; a < 15; ++a) {
    int bn = a0 + a;
    feat_t[t][a] = IF[(size_t)bn * 256 + t] + AE[(size_t)bn * 256 + t];
  }
  feat_t[t][15] = 0.f;
  __syncthreads();
  float acc[15];
  float bias = cv ? bwfc[col] : 0.f;
#pragma unroll
  for (int a = 0; a < 15; ++a) acc[a] = bias;
  const float* wp = Wwfc + col;
#pragma unroll 8
  for (int d = 0; d < 256; ++d) {
    float wv = cv ? wp[(size_t)d * C_NCOL] : 0.f;
#pragma unroll
    for (int a = 0; a < 15; ++a) acc[a] = fmaf(feat_t[d][a], wv, acc[a]);
  }
  if (cv) {
#pragma unroll
    for (int a = 0; a < 15; ++a)
      logits[(size_t)(a0 + a) * C_NCOL + col] = acc[a];
  }
}

__global__ __launch_bounds__(256) void dfa_softmax(float* __restrict__ wgt) {
  int bn = blockIdx.x;
  float* w = wgt + (size_t)bn * C_NCOL;
  __shared__ float buf[C_NCOL];
  int t = threadIdx.x;
  for (int i = t; i < C_NCOL; i += 256) buf[i] = w[i];
  __syncthreads();
  int g = t >> 5, lane = t & 31;
  float m = -1e30f;
  for (int s = lane; s < C_NSLOT; s += 32) m = fmaxf(m, buf[s * 8 + g]);
#pragma unroll
  for (int off = 16; off; off >>= 1) m = fmaxf(m, __shfl_xor(m, off, 32));
  float sum = 0.f;
  for (int s = lane; s < C_NSLOT; s += 32) {
    float e = expf(buf[s * 8 + g] - m);
    buf[s * 8 + g] = e;
    sum += e;
  }
#pragma unroll
  for (int off = 16; off; off >>= 1) sum += __shfl_xor(sum, off, 32);
  float inv = 1.f / sum;
  for (int s = lane; s < C_NSLOT; s += 32) w[s * 8 + g] = buf[s * 8 + g] * inv;
}

__global__ __launch_bounds__(128) void dfa_points(
    const float* __restrict__ IF, const float* __restrict__ anchor,
    const float* __restrict__ Wkps, const float* __restrict__ bkps,
    const float* __restrict__ projm, float2* __restrict__ grid) {
  int bn = blockIdx.x;
  int b = bn / C_NA;
  int t = threadIdx.x;
  __shared__ float kp[13][3];
  if (t < 39) {
    float acc = bkps[t];
    const float* f = IF + (size_t)bn * 256;
    for (int d = 0; d < 256; ++d) acc = fmaf(f[d], Wkps[d * 39 + t], acc);
    int p = t / 3, ax = t % 3;
    kp[p][ax] = anchor[(size_t)bn * 256 + ax] + acc;
  }
  __syncthreads();
  if (t < 78) {
    int c = t / 13, p = t % 13;
    const float* M = projm + (size_t)(b * 6 + c) * 16;
    float kx = kp[p][0], ky = kp[p][1], kz = kp[p][2];
    float x = M[0] * kx + M[1] * ky + M[2] * kz + M[3];
    float y = M[4] * kx + M[5] * ky + M[6] * kz + M[7];
    float z = M[8] * kx + M[9] * ky + M[10] * kz + M[11];
    float zc = fmaxf(z, 1e-5f);
    float inv = 1.0f / zc;
    grid[(size_t)bn * 78 + t] = make_float2(x * inv, y * inv);
  }
}

struct __align__(16) SlotInfo { int o[4]; float w[4]; };

__global__ __launch_bounds__(256) void dfa_agg_fb(
    const float* __restrict__ fm0, const float* __restrict__ fm1,
    const float* __restrict__ fm2, const float* __restrict__ fm3,
    const float2* __restrict__ grid, const float* __restrict__ wgt,
    const float* __restrict__ IF, const float* __restrict__ Wout,
    const float* __restrict__ bout, float* __restrict__ out) {
  int bn = blockIdx.x;
  int b = bn / C_NA;
  int t = threadIdx.x;
  int w = t >> 6, lane = t & 63;

  __shared__ SlotInfo slot[C_NSLOT];
  __shared__ int sflag[C_NSLOT];
  __shared__ float swgt[C_NCOL];
  __shared__ float part[4][256];
  __shared__ float fused[256];

  for (int i = t; i < C_NCOL; i += 256) swgt[i] = wgt[(size_t)bn * C_NCOL + i];

  for (int s = t; s < C_NSLOT; s += 256) {
    int c = s / 52, r = s % 52, l = r / 13, p = r % 13;
    float2 g2 = grid[(size_t)bn * 78 + c * 13 + p];
    int Wi = (l == 0) ? 176 : (l == 1) ? 88 : (l == 2) ? 44 : 22;
    int Hi = (l == 0) ? 64 : (l == 1) ? 32 : (l == 2) ? 16 : 8;
    float Wf = (float)Wi, Hf = (float)Hi;
    float ix = ((g2.x + 1.0f) * Wf - 1.0f) * 0.5f;
    float iy = ((g2.y + 1.0f) * Hf - 1.0f) * 0.5f;
    float ix0 = floorf(ix), iy0 = floorf(iy);
    float wx1 = ix - ix0, wy1 = iy - iy0;
    float wx0 = 1.f - wx1, wy0 = 1.f - wy1;
    bool vx0 = (ix0 >= 0.f) && (ix0 < Wf);
    bool vx1 = (ix0 + 1.f >= 0.f) && (ix0 + 1.f < Wf);
    bool vy0 = (iy0 >= 0.f) && (iy0 < Hf);
    bool vy1 = (iy0 + 1.f >= 0.f) && (iy0 + 1.f < Hf);
    int xi0 = (int)fminf(fmaxf(ix0, 0.f), Wf - 1.f);
    int xi1 = (int)fminf(fmaxf(ix0 + 1.f, 0.f), Wf - 1.f);
    int yi0 = (int)fminf(fmaxf(iy0, 0.f), Hf - 1.f);
    int yi1 = (int)fminf(fmaxf(iy0 + 1.f, 0.f), Hf - 1.f);
    int img = b * 6 + c;
    int HW = Wi * Hi;
    SlotInfo si;
    int ib = img * 256 * HW;
    si.o[0] = ib + yi0 * Wi + xi0;
    si.o[1] = ib + yi0 * Wi + xi1;
    si.o[2] = ib + yi1 * Wi + xi0;
    si.o[3] = ib + yi1 * Wi + xi1;
    si.w[0] = (vx0 && vy0) ? wy0 * wx0 : 0.f;
    si.w[1] = (vx1 && vy0) ? wy0 * wx1 : 0.f;
    si.w[2] = (vx0 && vy1) ? wy1 * wx0 : 0.f;
    si.w[3] = (vx1 && vy1) ? wy1 * wx1 : 0.f;
    slot[s] = si;
    sflag[s] = (si.w[0] + si.w[1] + si.w[2] + si.w[3] == 0.f) ? -1 : l;
  }
  __syncthreads();

  int g = lane >> 3;
  int ch = lane * 4;
  float4 acc = make_float4(0.f, 0.f, 0.f, 0.f);
  for (int s = w; s < C_NSLOT; s += 4) {
    int fl = sflag[s];
    if (fl < 0) continue;
    SlotInfo si = slot[s];
    float wg = swgt[s * 8 + g];
    const float* fp = (fl == 0) ? fm0 : (fl == 1) ? fm1 : (fl == 2) ? fm2 : fm3;
    int HW = (fl == 0) ? 11264 : (fl == 1) ? 2816 : (fl == 2) ? 704 : 176;
    float4 sv = make_float4(0.f, 0.f, 0.f, 0.f);
#pragma unroll
    for (int k = 0; k < 4; ++k) {
      if (si.w[k] != 0.f) {
        sv.x = fmaf(si.w[k], fp[si.o[k] + (size_t)(ch + 0) * HW], sv.x);
        sv.y = fmaf(si.w[k], fp[si.o[k] + (size_t)(ch + 1) * HW], sv.y);
        sv.z = fmaf(si.w[k], fp[si.o[k] + (size_t)(ch + 2) * HW], sv.z);
        sv.w = fmaf(si.w[k], fp[si.o[k] + (size_t)(ch + 3) * HW], sv.w);
      }
    }
    acc.x = fmaf(sv.x, wg, acc.x);
    acc.y = fmaf(sv.y, wg, acc.y);
    acc.z = fmaf(sv.z, wg, acc.z);
    acc.w = fmaf(sv.w, wg, acc.w);
  }
  *reinterpret_cast<float4*>(&part[w][ch]) = acc;
  __syncthreads();

  fused[t] = part[0][t] + part[1][t] + part[2][t] + part[3][t];
  __syncthreads();

  float o = bout[t] + IF[(size_t)bn * 256 + t];
#pragma unroll 4
  for (int d = 0; d < 256; ++d)
    o = fmaf(fused[d], Wout[d * 256 + t], o);
  out[(size_t)bn * 256 + t] = o;
}

// ---------------------------------------------------------------------------
extern "C" void kernel_launch(void* const* d_in, const int* in_sizes, int n_in,
                              void* d_out, int out_size, void* d_ws, size_t ws_size,
                              hipStream_t stream) {
  const float* IF     = (const float*)d_in[0];
  const float* anchor = (const float*)d_in[1];
  const float* AE     = (const float*)d_in[2];
  const float* fm0    = (const float*)d_in[3];
  const float* fm1    = (const float*)d_in[4];
  const float* fm2    = (const float*)d_in[5];
  const float* fm3    = (const float*)d_in[6];
  const float* projm  = (const float*)d_in[7];
  const float* Wkps   = (const float*)d_in[8];
  const float* bkps   = (const float*)d_in[9];
  const float* Wwfc   = (const float*)d_in[10];
  const float* bwfc   = (const float*)d_in[11];
  const float* Wout   = (const float*)d_in[12];
  const float* bout   = (const float*)d_in[13];
  float* out = (float*)d_out;
  char* ws = (char*)d_ws;

  bool full = ws_size >= (FM8_WS_BYTES + WGT16_WS_BYTES + WBT_WS_BYTES);
  if (full) {
    unsigned char* fmws = (unsigned char*)ws;                       // NHWC fp8
    unsigned short* wgt16 = (unsigned short*)(ws + FM8_WS_BYTES);
    unsigned short* wbt = (unsigned short*)(ws + FM8_WS_BYTES + WGT16_WS_BYTES);
    dfa_prep_wbt<<<39, 256, 0, stream>>>(Wwfc, wbt);
    dfa_stage1<<<1008, 256, 0, stream>>>(fm0, fm1, fm2, fm3, fmws,
                                         IF, AE, wbt, bwfc, wgt16);
    dfa_agg_full<<<1800, 256, 0, stream>>>(fmws, wgt16, IF, anchor, Wkps, bkps,
                                           projm, Wout, bout, out);
  } else {
    float* wgt  = (float*)ws;
    float2* grd = (float2*)(ws + 17971200ull);
    dfa_logits_gemm_fb<<<dim3(120, 10), 256, 0, stream>>>(IF, AE, Wwfc, bwfc, wgt);
    dfa_softmax<<<1800, 256, 0, stream>>>(wgt);
    dfa_points<<<1800, 128, 0, stream>>>(IF, anchor, Wkps, bkps, projm, grd);
    dfa_agg_fb<<<1800, 256, 0, stream>>>(fm0, fm1, fm2, fm3, grd, wgt,
                                         IF, Wout, bout, out);
  }
}

// Round 19
// 116.165 us; speedup vs baseline: 1.1999x; 1.0279x over previous
//
#include <hip/hip_runtime.h>
#include <hip/hip_bf16.h>

// Problem constants
#define C_NUM_CAMS 6
#define C_NUM_LEVELS 4
#define C_NUM_PTS 13
#define C_NUM_GROUPS 8
#define C_BS 2
#define C_NA 900
#define C_E 256
#define C_NSLOT 312      // C*L*P
#define C_NCOL 2496      // NSLOT * G
#define C_NANCH 1800     // BS*NA

// Level geometry: H 64,32,16,8; W 176,88,44,22; HW 11264,2816,704,176
// fp8 ws: 1 byte/elem, bases in bytes
#define LB0 0
#define LB1 34603008     // 12*11264*256
#define LB2 43253760     // +12*2816*256
#define LB3 45416448     // +12*704*256
#define FM8_WS_BYTES 45957120ull
#define WGT16_WS_BYTES 8985600ull  // 1800*2496*2 (bf16 logits)
#define WBT_WS_BYTES 1277952ull    // 2496*256*2

typedef float floatx2 __attribute__((ext_vector_type(2)));
typedef float f32x4 __attribute__((ext_vector_type(4)));
typedef short s16x8 __attribute__((ext_vector_type(8)));
typedef float f32x4v __attribute__((ext_vector_type(4)));

static __device__ __forceinline__ int pk_fp8(float a, float b, float c, float d) {
  int v = __builtin_amdgcn_cvt_pk_fp8_f32(a, b, 0, false);   // bytes 0,1
  v = __builtin_amdgcn_cvt_pk_fp8_f32(c, d, v, true);        // bytes 2,3
  return v;
}
static __device__ __forceinline__ unsigned short f2bf(float f) {
  __hip_bfloat16 h = __float2bfloat16(f);
  return *reinterpret_cast<unsigned short*>(&h);
}
static __device__ __forceinline__ float bf2f(unsigned short u) {
  unsigned int v = ((unsigned int)u) << 16;
  float f;
  __builtin_memcpy(&f, &v, 4);
  return f;
}

// ---------------------------------------------------------------------------
// K0: prep — coalesced transpose Wwfc f32[256][2496] -> Wbt bf16[2496][256].
// ---------------------------------------------------------------------------
__global__ __launch_bounds__(256) void dfa_prep_wbt(
    const float* __restrict__ W, unsigned short* __restrict__ Wbt) {
  __shared__ unsigned short tile[64][264];   // [c][d], 33.8 KB
  int t = threadIdx.x;
  int c0 = blockIdx.x * 64;
  int rA = t >> 4;          // 0..15
  int cA = (t & 15) * 4;    // 0..60
#pragma unroll
  for (int p = 0; p < 16; ++p) {
    int r = p * 16 + rA;
    f32x4 v = *(const f32x4*)(W + (size_t)r * C_NCOL + c0 + cA);
    tile[cA + 0][r] = f2bf(v.x);
    tile[cA + 1][r] = f2bf(v.y);
    tile[cA + 2][r] = f2bf(v.z);
    tile[cA + 3][r] = f2bf(v.w);
  }
  __syncthreads();
  int cB = t >> 5;          // 0..7
  int i4 = t & 31;          // 0..31
#pragma unroll
  for (int p = 0; p < 8; ++p) {
    int c = p * 8 + cB;
    int4 o = *(const int4*)&tile[c][i4 * 8];
    *(int4*)(Wbt + (size_t)(c0 + c) * 256 + i4 * 8) = o;
  }
}

// ---------------------------------------------------------------------------
// K1: merged stage-1 (high-occupancy ingest probe).
//   blocks [0,300):    logits GEMM via MFMA bf16 from Wbt -> bf16 logits
//   blocks [300,3132): NCHW f32 -> NHWC fp8 transpose, 64ch x 256px tiles.
// LDS 20.5 KB union -> ~7 blocks/CU (≈87% occupancy); f32x4 1KB-burst reads;
// 64B-cluster stores (R8-proven clean).
// ---------------------------------------------------------------------------
__global__ __launch_bounds__(256) void dfa_stage1(
    const float* __restrict__ fm0, const float* __restrict__ fm1,
    const float* __restrict__ fm2, const float* __restrict__ fm3,
    unsigned char* __restrict__ outw,
    const float* __restrict__ IF, const float* __restrict__ AE,
    const unsigned short* __restrict__ Wbt, const float* __restrict__ bwfc,
    unsigned short* __restrict__ logits) {
  __shared__ __align__(16) char smem[20544];
  int id = blockIdx.x;
  int t = threadIdx.x;
  int w = t >> 6, lane = t & 63;

  if (id >= 300) {
    // ---------------- transpose path: 64ch x 256px tiles ----------------
    int tid = id - 300;
    int (*lds)[260] = (int(*)[260])smem;   // [16][260] ints used = 16.6 KB
    const float* fm;
    int HW, strips;
    long long base;
    int rem;
    if (tid < 2112)      { rem = tid;        fm = fm0; HW = 11264; strips = 44; base = LB0; }
    else if (tid < 2640) { rem = tid - 2112; fm = fm1; HW = 2816;  strips = 11; base = LB1; }
    else if (tid < 2784) { rem = tid - 2640; fm = fm2; HW = 704;   strips = 3;  base = LB2; }
    else                 { rem = tid - 2784; fm = fm3; HW = 176;   strips = 1;  base = LB3; }
    int img   = rem / (strips * 4);
    int r2    = rem % (strips * 4);
    int cg    = r2 / strips;
    int strip = r2 % strips;
    int ch0 = cg * 64;
    int px0 = strip * 256;

    // phase A: wave w owns ch [ch0+w*16, +16); 4 quads x 4 rows, f32x4 each
    {
      int pxl = lane * 4;
      bool pv = (px0 + pxl) < HW;
      const float* src = fm + ((size_t)img * 256 + ch0 + w * 16) * HW + px0 + pxl;
      if (pv) {
#pragma unroll
        for (int cq = 0; cq < 4; ++cq) {
          const float* s = src + (size_t)(cq * 4) * HW;
          f32x4 r0 = *(const f32x4*)(s);
          f32x4 r1 = *(const f32x4*)(s + HW);
          f32x4 r2v = *(const f32x4*)(s + 2 * (size_t)HW);
          f32x4 r3 = *(const f32x4*)(s + 3 * (size_t)HW);
          int4 o;
          o.x = pk_fp8(r0.x, r1.x, r2v.x, r3.x);
          o.y = pk_fp8(r0.y, r1.y, r2v.y, r3.y);
          o.z = pk_fp8(r0.z, r1.z, r2v.z, r3.z);
          o.w = pk_fp8(r0.w, r1.w, r2v.w, r3.w);
          *(int4*)&lds[w * 4 + cq][pxl] = o;
        }
      }
    }
    __syncthreads();

    // phase B: 4 lanes per px write 64 B (4x int4) of this block's 64 ch
    {
      int ci = t & 3;          // int4 index within 64ch
      int pxb = t >> 2;        // 0..63
#pragma unroll
      for (int ps = 0; ps < 4; ++ps) {
        int px = ps * 64 + pxb;
        if (px0 + px < HW) {
          int4 o;
          o.x = lds[ci * 4 + 0][px];
          o.y = lds[ci * 4 + 1][px];
          o.z = lds[ci * 4 + 2][px];
          o.w = lds[ci * 4 + 3][px];
          *(int4*)(outw + base + ((long long)img * HW + px0 + px) * 256 + ch0 + ci * 16) = o;
        }
      }
    }
  } else {
    // ---------------- MFMA logits GEMM path ----------------
    typedef unsigned short us40[40];
    us40* As = (us40*)smem;                 // [128][40] = 10240 B
    us40* Bs = (us40*)(smem + 10240);       // [128][40]
    int m0 = (id % 15) * 128;
    int n0 = (id / 15) * 128;

    f32x4v acc[4][4];
#pragma unroll
    for (int mi = 0; mi < 4; ++mi)
#pragma unroll
      for (int ni = 0; ni < 4; ++ni)
        acc[mi][ni] = (f32x4v){0.f, 0.f, 0.f, 0.f};

    int r = t >> 1;              // 0..127 staging row
    int half = (t & 1) * 16;     // elem offset within 32-K slice
    int wr = (w >> 1) * 64, wc = (w & 1) * 64;
    int rsel = lane & 15;
    int koff = (lane >> 4) * 8;

    for (int ks = 0; ks < 8; ++ks) {
      int k0 = ks * 32;
      // A stage: feat = IF+AE, bf16
      {
        int a = m0 + r;
        s16x8 o0 = {0, 0, 0, 0, 0, 0, 0, 0};
        s16x8 o1 = {0, 0, 0, 0, 0, 0, 0, 0};
        if (a < C_NANCH) {
          const float* pI = IF + (size_t)a * 256 + k0 + half;
          const float* pA = AE + (size_t)a * 256 + k0 + half;
          f32x4 i0 = *(const f32x4*)(pI + 0), i1 = *(const f32x4*)(pI + 4);
          f32x4 i2 = *(const f32x4*)(pI + 8), i3 = *(const f32x4*)(pI + 12);
          f32x4 a0 = *(const f32x4*)(pA + 0), a1 = *(const f32x4*)(pA + 4);
          f32x4 a2 = *(const f32x4*)(pA + 8), a3 = *(const f32x4*)(pA + 12);
          o0[0] = (short)f2bf(i0.x + a0.x); o0[1] = (short)f2bf(i0.y + a0.y);
          o0[2] = (short)f2bf(i0.z + a0.z); o0[3] = (short)f2bf(i0.w + a0.w);
          o0[4] = (short)f2bf(i1.x + a1.x); o0[5] = (short)f2bf(i1.y + a1.y);
          o0[6] = (short)f2bf(i1.z + a1.z); o0[7] = (short)f2bf(i1.w + a1.w);
          o1[0] = (short)f2bf(i2.x + a2.x); o1[1] = (short)f2bf(i2.y + a2.y);
          o1[2] = (short)f2bf(i2.z + a2.z); o1[3] = (short)f2bf(i2.w + a2.w);
          o1[4] = (short)f2bf(i3.x + a3.x); o1[5] = (short)f2bf(i3.y + a3.y);
          o1[6] = (short)f2bf(i3.z + a3.z); o1[7] = (short)f2bf(i3.w + a3.w);
        }
        *(s16x8*)&As[r][half] = o0;
        *(s16x8*)&As[r][half + 8] = o1;
      }
      // B stage: Wbt row-major [col][k]
      {
        int c = n0 + r;
        s16x8 b0 = {0, 0, 0, 0, 0, 0, 0, 0};
        s16x8 b1 = {0, 0, 0, 0, 0, 0, 0, 0};
        if (c < C_NCOL) {
          const unsigned short* p = Wbt + (size_t)c * 256 + k0 + half;
          b0 = *(const s16x8*)(p);
          b1 = *(const s16x8*)(p + 8);
        }
        *(s16x8*)&Bs[r][half] = b0;
        *(s16x8*)&Bs[r][half + 8] = b1;
      }
      __syncthreads();

      s16x8 af[4], bf[4];
#pragma unroll
      for (int mi = 0; mi < 4; ++mi)
        af[mi] = *(const s16x8*)&As[wr + mi * 16 + rsel][koff];
#pragma unroll
      for (int ni = 0; ni < 4; ++ni)
        bf[ni] = *(const s16x8*)&Bs[wc + ni * 16 + rsel][koff];
#pragma unroll
      for (int mi = 0; mi < 4; ++mi)
#pragma unroll
        for (int ni = 0; ni < 4; ++ni)
          acc[mi][ni] = __builtin_amdgcn_mfma_f32_16x16x32_bf16(
              af[mi], bf[ni], acc[mi][ni], 0, 0, 0);
      __syncthreads();
    }

    // epilogue: logits(bf16) = acc + bias
    int rowb = (lane >> 4) * 4;
    int colo = lane & 15;
#pragma unroll
    for (int ni = 0; ni < 4; ++ni) {
      int col = n0 + wc + ni * 16 + colo;
      if (col >= C_NCOL) continue;
      float bias = bwfc[col];
#pragma unroll
      for (int mi = 0; mi < 4; ++mi) {
#pragma unroll
        for (int j = 0; j < 4; ++j) {
          int row = m0 + wr + mi * 16 + rowb + j;
          if (row < C_NANCH)
            logits[(size_t)row * C_NCOL + col] = f2bf(acc[mi][ni][j] + bias);
        }
      }
    }
  }
}

// ---------------------------------------------------------------------------
// K3: fused aggregation (fp8 NHWC ws, bf16 logits).  Block per anchor.
// ---------------------------------------------------------------------------
__global__ __launch_bounds__(256) void dfa_agg_full(
    const unsigned char* __restrict__ fmws,
    const unsigned short* __restrict__ logits,
    const float* __restrict__ IF, const float* __restrict__ anchor,
    const float* __restrict__ Wkps, const float* __restrict__ bkps,
    const float* __restrict__ projm,
    const float* __restrict__ Wout, const float* __restrict__ bout,
    float* __restrict__ out) {
  int bn = blockIdx.x;
  int b = bn / C_NA;
  int t = threadIdx.x;
  int w = t >> 6, lane = t & 63;

  __shared__ __align__(16) float logitsS[8 * 312];    // [g][s]; reused as centry
  __shared__ __align__(16) float swgt[C_NCOL];
  __shared__ unsigned short csS[1248];
  __shared__ __align__(16) float partS[8][256];
  __shared__ __align__(16) float fusedS[256];         // doubles as grid f2[78]
  __shared__ float kpS[13][3];
  __shared__ float invS[8];

  int2* centry = (int2*)logitsS;
  float2* gridS = (float2*)fusedS;

  for (int i = t; i < C_NCOL; i += 256) {
    float v = bf2f(logits[(size_t)bn * C_NCOL + i]);
    logitsS[(i & 7) * 312 + (i >> 3)] = v;
  }
  __syncthreads();

  {
    int g = t >> 5, l32 = t & 31;
    float* row = logitsS + g * 312;
    float m = -1e30f;
    for (int s = l32; s < C_NSLOT; s += 32) m = fmaxf(m, row[s]);
#pragma unroll
    for (int off = 16; off; off >>= 1) m = fmaxf(m, __shfl_xor(m, off, 32));
    float sum = 0.f;
    for (int s = l32; s < C_NSLOT; s += 32) {
      float e = __expf(row[s] - m);
      row[s] = e;
      sum += e;
    }
#pragma unroll
    for (int off = 16; off; off >>= 1) sum += __shfl_xor(sum, off, 32);
    if (l32 == 0) invS[g] = 1.f / sum;
  }
  __syncthreads();

  for (int i = t; i < C_NCOL; i += 256)
    swgt[i] = logitsS[(i & 7) * 312 + (i >> 3)] * invS[i & 7];
  if (t < 39) {
    const float* f = IF + (size_t)bn * 256;
    float a0 = 0.f, a1 = 0.f, a2 = 0.f, a3 = 0.f;
    for (int d = 0; d < 256; d += 4) {
      a0 = fmaf(f[d + 0], Wkps[(d + 0) * 39 + t], a0);
      a1 = fmaf(f[d + 1], Wkps[(d + 1) * 39 + t], a1);
      a2 = fmaf(f[d + 2], Wkps[(d + 2) * 39 + t], a2);
      a3 = fmaf(f[d + 3], Wkps[(d + 3) * 39 + t], a3);
    }
    float acc = bkps[t] + ((a0 + a1) + (a2 + a3));
    int p = t / 3, ax = t % 3;
    kpS[p][ax] = anchor[(size_t)bn * 256 + ax] + acc;
  }
  __syncthreads();

  if (t < 78) {
    int c = t / 13, p = t % 13;
    const float* M = projm + (size_t)(b * 6 + c) * 16;
    float kx = kpS[p][0], ky = kpS[p][1], kz = kpS[p][2];
    float x = M[0] * kx + M[1] * ky + M[2] * kz + M[3];
    float y = M[4] * kx + M[5] * ky + M[6] * kz + M[7];
    float z = M[8] * kx + M[9] * ky + M[10] * kz + M[11];
    float zc = fmaxf(z, 1e-5f);
    float inv = 1.0f / zc;
    gridS[t] = make_float2(x * inv, y * inv);
  }
  __syncthreads();

  int cnt = 0;
  {
    int ebase = w * 312;
#pragma unroll
    for (int r = 0; r < 2; ++r) {
      int li = r * 64 + lane;
      bool lv = li < 78;
      int s = w * 78 + (lv ? li : 0);
      int cam = s / 52, rr = s % 52, l = rr / 13, p = rr % 13;
      float2 g2 = gridS[cam * 13 + p];
      int Wi = (l == 0) ? 176 : (l == 1) ? 88 : (l == 2) ? 44 : 22;
      int Hi = (l == 0) ? 64 : (l == 1) ? 32 : (l == 2) ? 16 : 8;
      float Wf = (float)Wi, Hf = (float)Hi;
      float ix = ((g2.x + 1.0f) * Wf - 1.0f) * 0.5f;
      float iy = ((g2.y + 1.0f) * Hf - 1.0f) * 0.5f;
      float ix0 = floorf(ix), iy0 = floorf(iy);
      float wx1 = ix - ix0, wy1 = iy - iy0;
      float wx0 = 1.f - wx1, wy0 = 1.f - wy1;
      bool vx0 = (ix0 >= 0.f) && (ix0 < Wf);
      bool vx1 = (ix0 + 1.f >= 0.f) && (ix0 + 1.f < Wf);
      bool vy0 = (iy0 >= 0.f) && (iy0 < Hf);
      bool vy1 = (iy0 + 1.f >= 0.f) && (iy0 + 1.f < Hf);
      int xi0 = (int)fminf(fmaxf(ix0, 0.f), Wf - 1.f);
      int xi1 = (int)fminf(fmaxf(ix0 + 1.f, 0.f), Wf - 1.f);
      int yi0 = (int)fminf(fmaxf(iy0, 0.f), Hf - 1.f);
      int yi1 = (int)fminf(fmaxf(iy0 + 1.f, 0.f), Hf - 1.f);
      int lb = (l == 0) ? LB0 : (l == 1) ? LB1 : (l == 2) ? LB2 : LB3;
      int ib = lb + (b * 6 + cam) * Wi * Hi * 256;
      float cw[4];
      int co[4];
      cw[0] = (vx0 && vy0) ? wy0 * wx0 : 0.f;
      cw[1] = (vx1 && vy0) ? wy0 * wx1 : 0.f;
      cw[2] = (vx0 && vy1) ? wy1 * wx0 : 0.f;
      cw[3] = (vx1 && vy1) ? wy1 * wx1 : 0.f;
      co[0] = ib + (yi0 * Wi + xi0) * 256;
      co[1] = ib + (yi0 * Wi + xi1) * 256;
      co[2] = ib + (yi1 * Wi + xi0) * 256;
      co[3] = ib + (yi1 * Wi + xi1) * 256;
      unsigned short sw8 = (unsigned short)(s * 8);
#pragma unroll
      for (int k = 0; k < 4; ++k) {
        bool v = lv && (cw[k] != 0.f);
        unsigned long long mb = __ballot(v);
        int pos = cnt + __popcll(mb & ((1ull << lane) - 1ull));
        if (v) {
          centry[ebase + pos] = make_int2(co[k], __float_as_int(cw[k]));
          csS[ebase + pos] = sw8;
        }
        cnt += (int)__popcll(mb);
      }
    }
    if (cnt & 1) {
      if (lane == 0) {
        centry[ebase + cnt] = make_int2(0, 0);
        csS[ebase + cnt] = 0;
      }
      cnt++;
    }
  }

  int half = lane >> 5, l32 = lane & 31;
  int ch = l32 * 8;
  int g = l32 >> 2;
  float acc[8];
#pragma unroll
  for (int j = 0; j < 8; ++j) acc[j] = 0.f;
  {
    int ebase = w * 312;
    int nIter = cnt >> 1;
#pragma unroll 8
    for (int i = 0; i < nIter; ++i) {
      int idx = ebase + 2 * i + half;
      int2 e = centry[idx];
      float wgt_s = swgt[(int)csS[idx] + g];
      float cw = __int_as_float(e.y) * wgt_s;
      int2 u = *reinterpret_cast<const int2*>(fmws + e.x + ch);
      floatx2 p0 = __builtin_amdgcn_cvt_pk_f32_fp8(u.x, false);
      floatx2 p1 = __builtin_amdgcn_cvt_pk_f32_fp8(u.x, true);
      floatx2 p2 = __builtin_amdgcn_cvt_pk_f32_fp8(u.y, false);
      floatx2 p3 = __builtin_amdgcn_cvt_pk_f32_fp8(u.y, true);
      acc[0] = fmaf(cw, p0.x, acc[0]);
      acc[1] = fmaf(cw, p0.y, acc[1]);
      acc[2] = fmaf(cw, p1.x, acc[2]);
      acc[3] = fmaf(cw, p1.y, acc[3]);
      acc[4] = fmaf(cw, p2.x, acc[4]);
      acc[5] = fmaf(cw, p2.y, acc[5]);
      acc[6] = fmaf(cw, p3.x, acc[6]);
      acc[7] = fmaf(cw, p3.y, acc[7]);
    }
  }
  {
    int row = w * 2 + half;
    float4 v0 = make_float4(acc[0], acc[1], acc[2], acc[3]);
    float4 v1 = make_float4(acc[4], acc[5], acc[6], acc[7]);
    *reinterpret_cast<float4*>(&partS[row][ch]) = v0;
    *reinterpret_cast<float4*>(&partS[row][ch + 4]) = v1;
  }
  __syncthreads();

  float fv = 0.f;
#pragma unroll
  for (int r = 0; r < 8; ++r) fv += partS[r][t];
  fusedS[t] = fv;
  __syncthreads();

  float o = bout[t] + IF[(size_t)bn * 256 + t];
#pragma unroll 8
  for (int d = 0; d < 256; ++d)
    o = fmaf(fusedS[d], Wout[d * 256 + t], o);
  out[(size_t)bn * 256 + t] = o;
}

// ---------------------------------------------------------------------------
// Fallback path (small ws): f32 logits GEMM + softmax + points + NCHW agg
// ---------------------------------------------------------------------------
__global__ __launch_bounds__(256) void dfa_logits_gemm_fb(
    const float* __restrict__ IF, const float* __restrict__ AE,
    const float* __restrict__ Wwfc, const float* __restrict__ bwfc,
    float* __restrict__ logits) {
  __shared__ float feat_t[256][16];
  int t = threadIdx.x;
  int a0 = blockIdx.x * 15;
  int col = blockIdx.y * 256 + t;
  bool cv = col < C_NCOL;
#pragma unroll
  for (int a = 0; a < 15; ++a) {
    int bn = a0 + a;
    feat_t[t][a] = IF[(size_t)bn * 256 + t] + AE[(size_t)bn * 256 + t];
  }
  feat_t[t][15] = 0.f;
  __syncthreads();
  float acc[15];
  float bias = cv ? bwfc[col] : 0.f;
#pragma unroll
  for (int a = 0; a < 15; ++a) acc[a] = bias;
  const float* wp = Wwfc + col;
#pragma unroll 8
  for (int d = 0; d < 256; ++d) {
    float wv = cv ? wp[(size_t)d * C_NCOL] : 0.f;
#pragma unroll
    for (int a = 0; a < 15; ++a) acc[a] = fmaf(feat_t[d][a], wv, acc[a]);
  }
  if (cv) {
#pragma unroll
    for (int a = 0; a < 15; ++a)
      logits[(size_t)(a0 + a) * C_NCOL + col] = acc[a];
  }
}

__global__ __launch_bounds__(256) void dfa_softmax(float* __restrict__ wgt) {
  int bn = blockIdx.x;
  float* w = wgt + (size_t)bn * C_NCOL;
  __shared__ float buf[C_NCOL];
  int t = threadIdx.x;
  for (int i = t; i < C_NCOL; i += 256) buf[i] = w[i];
  __syncthreads();
  int g = t >> 5, lane = t & 31;
  float m = -1e30f;
  for (int s = lane; s < C_NSLOT; s += 32) m = fmaxf(m, buf[s * 8 + g]);
#pragma unroll
  for (int off = 16; off; off >>= 1) m = fmaxf(m, __shfl_xor(m, off, 32));
  float sum = 0.f;
  for (int s = lane; s < C_NSLOT; s += 32) {
    float e = expf(buf[s * 8 + g] - m);
    buf[s * 8 + g] = e;
    sum += e;
  }
#pragma unroll
  for (int off = 16; off; off >>= 1) sum += __shfl_xor(sum, off, 32);
  float inv = 1.f / sum;
  for (int s = lane; s < C_NSLOT; s += 32) w[s * 8 + g] = buf[s * 8 + g] * inv;
}

__global__ __launch_bounds__(128) void dfa_points(
    const float* __restrict__ IF, const float* __restrict__ anchor,
    const float* __restrict__ Wkps, const float* __restrict__ bkps,
    const float* __restrict__ projm, float2* __restrict__ grid) {
  int bn = blockIdx.x;
  int b = bn / C_NA;
  int t = threadIdx.x;
  __shared__ float kp[13][3];
  if (t < 39) {
    float acc = bkps[t];
    const float* f = IF + (size_t)bn * 256;
    for (int d = 0; d < 256; ++d) acc = fmaf(f[d], Wkps[d * 39 + t], acc);
    int p = t / 3, ax = t % 3;
    kp[p][ax] = anchor[(size_t)bn * 256 + ax] + acc;
  }
  __syncthreads();
  if (t < 78) {
    int c = t / 13, p = t % 13;
    const float* M = projm + (size_t)(b * 6 + c) * 16;
    float kx = kp[p][0], ky = kp[p][1], kz = kp[p][2];
    float x = M[0] * kx + M[1] * ky + M[2] * kz + M[3];
    float y = M[4] * kx + M[5] * ky + M[6] * kz + M[7];
    float z = M[8] * kx + M[9] * ky + M[10] * kz + M[11];
    float zc = fmaxf(z, 1e-5f);
    float inv = 1.0f / zc;
    grid[(size_t)bn * 78 + t] = make_float2(x * inv, y * inv);
  }
}

struct __align__(16) SlotInfo { int o[4]; float w[4]; };

__global__ __launch_bounds__(256) void dfa_agg_fb(
    const float* __restrict__ fm0, const float* __restrict__ fm1,
    const float* __restrict__ fm2, const float* __restrict__ fm3,
    const float2* __restrict__ grid, const float* __restrict__ wgt,
    const float* __restrict__ IF, const float* __restrict__ Wout,
    const float* __restrict__ bout, float* __restrict__ out) {
  int bn = blockIdx.x;
  int b = bn / C_NA;
  int t = threadIdx.x;
  int w = t >> 6, lane = t & 63;

  __shared__ SlotInfo slot[C_NSLOT];
  __shared__ int sflag[C_NSLOT];
  __shared__ float swgt[C_NCOL];
  __shared__ float part[4][256];
  __shared__ float fused[256];

  for (int i = t; i < C_NCOL; i += 256) swgt[i] = wgt[(size_t)bn * C_NCOL + i];

  for (int s = t; s < C_NSLOT; s += 256) {
    int c = s / 52, r = s % 52, l = r / 13, p = r % 13;
    float2 g2 = grid[(size_t)bn * 78 + c * 13 + p];
    int Wi = (l == 0) ? 176 : (l == 1) ? 88 : (l == 2) ? 44 : 22;
    int Hi = (l == 0) ? 64 : (l == 1) ? 32 : (l == 2) ? 16 : 8;
    float Wf = (float)Wi, Hf = (float)Hi;
    float ix = ((g2.x + 1.0f) * Wf - 1.0f) * 0.5f;
    float iy = ((g2.y + 1.0f) * Hf - 1.0f) * 0.5f;
    float ix0 = floorf(ix), iy0 = floorf(iy);
    float wx1 = ix - ix0, wy1 = iy - iy0;
    float wx0 = 1.f - wx1, wy0 = 1.f - wy1;
    bool vx0 = (ix0 >= 0.f) && (ix0 < Wf);
    bool vx1 = (ix0 + 1.f >= 0.f) && (ix0 + 1.f < Wf);
    bool vy0 = (iy0 >= 0.f) && (iy0 < Hf);
    bool vy1 = (iy0 + 1.f >= 0.f) && (iy0 + 1.f < Hf);
    int xi0 = (int)fminf(fmaxf(ix0, 0.f), Wf - 1.f);
    int xi1 = (int)fminf(fmaxf(ix0 + 1.f, 0.f), Wf - 1.f);
    int yi0 = (int)fminf(fmaxf(iy0, 0.f), Hf - 1.f);
    int yi1 = (int)fminf(fmaxf(iy0 + 1.f, 0.f), Hf - 1.f);
    int img = b * 6 + c;
    int HW = Wi * Hi;
    SlotInfo si;
    int ib = img * 256 * HW;
    si.o[0] = ib + yi0 * Wi + xi0;
    si.o[1] = ib + yi0 * Wi + xi1;
    si.o[2] = ib + yi1 * Wi + xi0;
    si.o[3] = ib + yi1 * Wi + xi1;
    si.w[0] = (vx0 && vy0) ? wy0 * wx0 : 0.f;
    si.w[1] = (vx1 && vy0) ? wy0 * wx1 : 0.f;
    si.w[2] = (vx0 && vy1) ? wy1 * wx0 : 0.f;
    si.w[3] = (vx1 && vy1) ? wy1 * wx1 : 0.f;
    slot[s] = si;
    sflag[s] = (si.w[0] + si.w[1] + si.w[2] + si.w[3] == 0.f) ? -1 : l;
  }
  __syncthreads();

  int g = lane >> 3;
  int ch = lane * 4;
  float4 acc = make_float4(0.f, 0.f, 0.f, 0.f);
  for (int s = w; s < C_NSLOT; s += 4) {
    int fl = sflag[s];
    if (fl < 0) continue;
    SlotInfo si = slot[s];
    float wg = swgt[s * 8 + g];
    const float* fp = (fl == 0) ? fm0 : (fl == 1) ? fm1 : (fl == 2) ? fm2 : fm3;
    int HW = (fl == 0) ? 11264 : (fl == 1) ? 2816 : (fl == 2) ? 704 : 176;
    float4 sv = make_float4(0.f, 0.f, 0.f, 0.f);
#pragma unroll
    for (int k = 0; k < 4; ++k) {
      if (si.w[k] != 0.f) {
        sv.x = fmaf(si.w[k], fp[si.o[k] + (size_t)(ch + 0) * HW], sv.x);
        sv.y = fmaf(si.w[k], fp[si.o[k] + (size_t)(ch + 1) * HW], sv.y);
        sv.z = fmaf(si.w[k], fp[si.o[k] + (size_t)(ch + 2) * HW], sv.z);
        sv.w = fmaf(si.w[k], fp[si.o[k] + (size_t)(ch + 3) * HW], sv.w);
      }
    }
    acc.x = fmaf(sv.x, wg, acc.x);
    acc.y = fmaf(sv.y, wg, acc.y);
    acc.z = fmaf(sv.z, wg, acc.z);
    acc.w = fmaf(sv.w, wg, acc.w);
  }
  *reinterpret_cast<float4*>(&part[w][ch]) = acc;
  __syncthreads();

  fused[t] = part[0][t] + part[1][t] + part[2][t] + part[3][t];
  __syncthreads();

  float o = bout[t] + IF[(size_t)bn * 256 + t];
#pragma unroll 4
  for (int d = 0; d < 256; ++d)
    o = fmaf(fused[d], Wout[d * 256 + t], o);
  out[(size_t)bn * 256 + t] = o;
}

// ---------------------------------------------------------------------------
extern "C" void kernel_launch(void* const* d_in, const int* in_sizes, int n_in,
                              void* d_out, int out_size, void* d_ws, size_t ws_size,
                              hipStream_t stream) {
  const float* IF     = (const float*)d_in[0];
  const float* anchor = (const float*)d_in[1];
  const float* AE     = (const float*)d_in[2];
  const float* fm0    = (const float*)d_in[3];
  const float* fm1    = (const float*)d_in[4];
  const float* fm2    = (const float*)d_in[5];
  const float* fm3    = (const float*)d_in[6];
  const float* projm  = (const float*)d_in[7];
  const float* Wkps   = (const float*)d_in[8];
  const float* bkps   = (const float*)d_in[9];
  const float* Wwfc   = (const float*)d_in[10];
  const float* bwfc   = (const float*)d_in[11];
  const float* Wout   = (const float*)d_in[12];
  const float* bout   = (const float*)d_in[13];
  float* out = (float*)d_out;
  char* ws = (char*)d_ws;

  bool full = ws_size >= (FM8_WS_BYTES + WGT16_WS_BYTES + WBT_WS_BYTES);
  if (full) {
    unsigned char* fmws = (unsigned char*)ws;                       // NHWC fp8
    unsigned short* wgt16 = (unsigned short*)(ws + FM8_WS_BYTES);
    unsigned short* wbt = (unsigned short*)(ws + FM8_WS_BYTES + WGT16_WS_BYTES);
    dfa_prep_wbt<<<39, 256, 0, stream>>>(Wwfc, wbt);
    dfa_stage1<<<3132, 256, 0, stream>>>(fm0, fm1, fm2, fm3, fmws,
                                         IF, AE, wbt, bwfc, wgt16);
    dfa_agg_full<<<1800, 256, 0, stream>>>(fmws, wgt16, IF, anchor, Wkps, bkps,
                                           projm, Wout, bout, out);
  } else {
    float* wgt  = (float*)ws;
    float2* grd = (float2*)(ws + 17971200ull);
    dfa_logits_gemm_fb<<<dim3(120, 10), 256, 0, stream>>>(IF, AE, Wwfc, bwfc, wgt);
    dfa_softmax<<<1800, 256, 0, stream>>>(wgt);
    dfa_points<<<1800, 128, 0, stream>>>(IF, anchor, Wkps, bkps, projm, grd);
    dfa_agg_fb<<<1800, 256, 0, stream>>>(fm0, fm1, fm2, fm3, grd, wgt,
                                         IF, Wout, bout, out);
  }
}